// Round 7
// baseline (401.340 us; speedup 1.0000x reference)
//
#include <hip/hip_runtime.h>
#include <hip/hip_bf16.h>
#include <math.h>

#define DEV __device__ __forceinline__

constexpr int BATCH = 4096;
constexpr int NBA = 512;    // pool/minmax blocks
constexpr int NBB = 1024;   // conv1-stats blocks (4 img each)
constexpr int NBC = 1024;   // fused conv blocks (4 img each, sequential pipelined)
constexpr int NBE = 512;    // fc1 blocks (8 img each)
constexpr int NBW = 16;     // kw1/kw3 blocks

// workspace layout (float offsets)
constexpr size_t OFF_POOLED = 0;                            // 4096*196
constexpr size_t OFF_Y2P = OFF_POOLED + (size_t)BATCH*196;  // 4096*400 (pooled conv2 out)
constexpr size_t OFF_H3  = OFF_Y2P + (size_t)BATCH*400;     // 4096*128 (fc1 post-relu)
constexpr size_t OFF_ST2 = OFF_H3;                          // 16*NBC*4, consumed by kstat2 BEFORE ke writes H3
constexpr size_t OFF_W1  = OFF_H3 + (size_t)BATCH*128;      // 576
constexpr size_t OFF_W2  = OFF_W1 + 576;                    // W2 as bf16 hi[9216]+lo[9216] ushorts, [oc][kykx*64+ic]
constexpr size_t OFF_W3  = OFF_W2 + 9216;                   // 51200, layout [k*128+oc]
constexpr size_t OFF_W4  = OFF_W3 + 51200;                  // 1280, natural [oc*128+k]
constexpr size_t OFF_WSC = OFF_W4 + 1280;                   // 4 layer scales
constexpr size_t OFF_ST1 = OFF_WSC + 4;                     // 64*NBB*4 conv1 channel stats partials
constexpr size_t OFF_BN1 = OFF_ST1 + (size_t)64*NBB*4;      // 64*4 {mean, sd, tmin, tmax}
constexpr size_t OFF_BN2 = OFF_BN1 + 256;                   // 16*4
constexpr size_t OFF_GMM = OFF_BN2 + 64;                    // 8 encoded-uint global min/max slots
// [0]=pooled min [1]=pooled max [2]=bn1 tmin [3]=bn1 tmax [4]=bn2 tmin [5]=bn2 tmax [6]=fc1 min [7]=fc1 max
constexpr size_t OFF_ONS = OFF_GMM + 8;                     // 4 floats: sum(hw_one) per layer
constexpr size_t OFF_T   = OFF_ONS + 4;                     // 4 uints: selection thresholds
constexpr size_t OFF_HIST= OFF_T + 4;                       // 4*2048 uints global histograms

typedef __attribute__((ext_vector_type(8))) short bf16x8;
typedef __attribute__((ext_vector_type(4))) float f32x4;

struct InPtrs {
  const float* x;
  const float* sc[4];
  const float* sg[4];
  const float* on[4];
  const float* ze[4];
  const int* qb;
};

// kw block partition: 16 blocks over 4 layers
__constant__ const int KW_L[16]  ={0,1,1,2,2,2,2,2,2,2,2,2,2,2,2,3};
__constant__ const int KW_S[16]  ={0,0,1,0,1,2,3,4,5,6,7,8,9,10,11,0};
__constant__ const int KW_NB[4]  ={1,2,12,1};
__constant__ const int KW_N[4]   ={576,9216,51200,1280};
__constant__ const int KW_FAN[4] ={9,576,400,128};

DEV unsigned fenc(float f){ unsigned u=__float_as_uint(f); return (u&0x80000000u)? ~u : (u|0x80000000u); }
DEV float fdec(unsigned e){ return __uint_as_float((e&0x80000000u)? (e&0x7fffffffu) : ~e); }
DEV unsigned short f2bf(float f){ unsigned u=__float_as_uint(f); return (unsigned short)((u + 0x7fffu + ((u>>16)&1u))>>16); }

DEV float blk_sum(float v, float* red, int t){
  red[t]=v; __syncthreads();
  for (int s=128;s>0;s>>=1){ if(t<s) red[t]+=red[t+s]; __syncthreads(); }
  float r=red[0]; __syncthreads();
  return r;
}
DEV float blk_min(float v, float* red, int t){
  red[t]=v; __syncthreads();
  for (int s=128;s>0;s>>=1){ if(t<s) red[t]=fminf(red[t],red[t+s]); __syncthreads(); }
  float r=red[0]; __syncthreads();
  return r;
}
DEV float blk_max(float v, float* red, int t){
  red[t]=v; __syncthreads();
  for (int s=128;s>0;s>>=1){ if(t<s) red[t]=fmaxf(red[t],red[t+s]); __syncthreads(); }
  float r=red[0]; __syncthreads();
  return r;
}

DEV void loadrow16(const float* p, float* r){
  const float4* q=(const float4*)p;
  float4 a=q[0],b=q[1],c=q[2],d=q[3];
  r[0]=a.x;r[1]=a.y;r[2]=a.z;r[3]=a.w;
  r[4]=b.x;r[5]=b.y;r[6]=b.z;r[7]=b.w;
  r[8]=c.x;r[9]=c.y;r[10]=c.z;r[11]=c.w;
  r[12]=d.x;r[13]=d.y;r[14]=d.z;r[15]=d.w;
}

DEV float conv9(const float* ra,const float* rb,const float* rc,const float* w,int x){
  float a=ra[x]*w[0];
  a=fmaf(ra[x+1],w[1],a); a=fmaf(ra[x+2],w[2],a);
  a=fmaf(rb[x],w[3],a);   a=fmaf(rb[x+1],w[4],a); a=fmaf(rb[x+2],w[5],a);
  a=fmaf(rc[x],w[6],a);   a=fmaf(rc[x+1],w[7],a); a=fmaf(rc[x+2],w[8],a);
  return a;
}

DEV void c1row_stat(const float* ra,const float* rb,const float* rc,const float* w,
                    float inv_s1w,float& sum,float& sq,float& vmn,float& vmx){
  #pragma unroll
  for (int x=0;x<12;++x){
    float v=conv9(ra,rb,rc,w,x)*inv_s1w;
    sum+=v; sq=fmaf(v,v,sq); vmn=fminf(vmn,v); vmx=fmaxf(vmx,v);
  }
}

DEV void c1row1(const float* ra,const float* rb,const float* rc,const float* w,
                float Ac,float Bc,float inv_s2,float lvf,int y,int ch,unsigned short* actA){
  #pragma unroll
  for (int x=0;x<12;++x){
    float a=conv9(ra,rb,rc,w,x);
    float f=fminf(rintf(fmaxf(fmaf(a,Ac,Bc),0.f)*inv_s2),lvf);  // integer 0..255, exact in bf16
    actA[(y*12+x)*72+ch]=(unsigned short)(__float_as_uint(f)>>16);
  }
}

// find bucket from top with 1024 threads; nbins<=2048
DEV int2 find_hist(const int* hist, int nbins, int kk, int t, int* suf, int* sh2){
  const int G=(nbins+1023)>>10;
  const int lo=t*G, hi=(lo+G<nbins)?(lo+G):nbins;
  int g=0;
  for (int b=lo;b<hi;++b) g+=hist[b];
  suf[t]=g; __syncthreads();
  #pragma unroll
  for (int s=1;s<1024;s<<=1){
    int add=(t+s<1024)?suf[t+s]:0;
    __syncthreads();
    suf[t]+=add;
    __syncthreads();
  }
  const int S=suf[t];
  const int Snext=(t<1023)?suf[t+1]:0;
  if (S>=kk && Snext<kk){
    int c2=Snext;
    for (int b=hi-1;b>=lo;--b){
      c2+=hist[b];
      if (c2>=kk){ sh2[0]=b; sh2[1]=kk-(c2-hist[b]); break; }
    }
  }
  __syncthreads();
  int2 r=make_int2(sh2[0],sh2[1]);
  __syncthreads();
  return r;
}

// ---------------- KA: 2x2 maxpool + global pooled min/max; block 0 zeroes hist/GMM/ONS ----------------
__global__ __launch_bounds__(256) void ka_kernel(InPtrs in, float* __restrict__ ws){
  const int t=threadIdx.x, blk=blockIdx.x;
  if (blk==0){
    unsigned* H=(unsigned*)(ws+OFF_HIST);
    for (int i=t;i<8192;i+=256) H[i]=0u;
    if (t<8) ((unsigned*)(ws+OFF_GMM))[t]=(t&1)? 0u : 0xFFFFFFFFu;
    if (t<4) ws[OFF_ONS+t]=0.f;
  }
  const float* x=in.x;
  float* pooled=ws+OFF_POOLED;
  float lmn=3.4e38f, lmx=-3.4e38f;
  for (int p=blk*256+t; p<BATCH*196; p+=NBA*256){
    int b=p/196, r=p-b*196;
    int oy=r/14, ox=r-oy*14;
    const float* px=x+b*784+oy*56+ox*2;
    float m=fmaxf(fmaxf(px[0],px[1]),fmaxf(px[28],px[29]));
    pooled[p]=m;
    lmn=fminf(lmn,m); lmx=fmaxf(lmx,m);
  }
  #pragma unroll
  for (int d=1;d<64;d<<=1){
    lmn=fminf(lmn,__shfl_xor(lmn,d));
    lmx=fmaxf(lmx,__shfl_xor(lmx,d));
  }
  if ((t&63)==0){
    unsigned* U=(unsigned*)(ws+OFF_GMM);
    atomicMin(&U[0],fenc(lmn));
    atomicMax(&U[1],fenc(lmx));
  }
}

// ---------------- KW1: per-slice |score| histogram (bits[30:20]) + sum(hw_one) ----------------
__global__ __launch_bounds__(256) void kw1_kernel(InPtrs in, float* __restrict__ ws){
  const int t=threadIdx.x, blk=blockIdx.x;
  const int L=KW_L[blk], s=KW_S[blk], nb=KW_NB[L];
  const int n4=KW_N[L]>>2;
  const int lo=(int)(((long long)n4*s)/nb), hi=(int)(((long long)n4*(s+1))/nb);
  const float4* sc4=(const float4*)in.sc[L];
  const float4* on4=(const float4*)in.on[L];
  __shared__ int h[2048];
  for (int i=t;i<2048;i+=256) h[i]=0;
  __syncthreads();
  float onsum=0.f;
  for (int i=lo+t;i<hi;i+=256){
    float4 v=sc4[i];
    atomicAdd(&h[(__float_as_uint(v.x)&0x7fffffffu)>>20],1);
    atomicAdd(&h[(__float_as_uint(v.y)&0x7fffffffu)>>20],1);
    atomicAdd(&h[(__float_as_uint(v.z)&0x7fffffffu)>>20],1);
    atomicAdd(&h[(__float_as_uint(v.w)&0x7fffffffu)>>20],1);
    float4 o=on4[i];
    onsum+=(o.x+o.y)+(o.z+o.w);
  }
  __syncthreads();
  unsigned* GH=(unsigned*)(ws+OFF_HIST);
  for (int i=t;i<2048;i+=256){ int c=h[i]; if (c) atomicAdd(&GH[L*2048+i],(unsigned)c); }
  __shared__ float red[256];
  float S=blk_sum(onsum,red,t);
  if (t==0) atomicAdd(&ws[OFF_ONS+L],S);
}

// ---------------- KW2: exact 3-pass radix select threshold per layer ----------------
__global__ __launch_bounds__(1024) void kw2_kernel(InPtrs in, float* __restrict__ ws){
  const int t=threadIdx.x;
  const int L=blockIdx.x;
  const int N=KW_N[L];
  const int n4=N>>2;
  const int K=N>>1;
  const float4* sc4=(const float4*)in.sc[L];
  __shared__ int hist[2048];
  __shared__ int suf[1024];
  __shared__ int sh2[2];
  const unsigned* GH=(const unsigned*)(ws+OFF_HIST);
  for (int i=t;i<2048;i+=1024) hist[i]=(int)GH[L*2048+i];
  __syncthreads();
  int2 f1=find_hist(hist,2048,K,t,suf,sh2);
  const unsigned b0=(unsigned)f1.x; const int r1=f1.y;

  hist[t]=0;
  __syncthreads();
  for (int i=t;i<n4;i+=1024){
    float4 v=sc4[i];
    unsigned ux=__float_as_uint(v.x)&0x7fffffffu;
    unsigned uy=__float_as_uint(v.y)&0x7fffffffu;
    unsigned uz=__float_as_uint(v.z)&0x7fffffffu;
    unsigned uw=__float_as_uint(v.w)&0x7fffffffu;
    if ((ux>>20)==b0) atomicAdd(&hist[(ux>>10)&1023u],1);
    if ((uy>>20)==b0) atomicAdd(&hist[(uy>>10)&1023u],1);
    if ((uz>>20)==b0) atomicAdd(&hist[(uz>>10)&1023u],1);
    if ((uw>>20)==b0) atomicAdd(&hist[(uw>>10)&1023u],1);
  }
  __syncthreads();
  int2 f2=find_hist(hist,1024,r1,t,suf,sh2);
  const unsigned b1=(unsigned)f2.x; const int r2=f2.y;
  const unsigned pre=(b0<<10)|b1;

  hist[t]=0;
  __syncthreads();
  for (int i=t;i<n4;i+=1024){
    float4 v=sc4[i];
    unsigned ux=__float_as_uint(v.x)&0x7fffffffu;
    unsigned uy=__float_as_uint(v.y)&0x7fffffffu;
    unsigned uz=__float_as_uint(v.z)&0x7fffffffu;
    unsigned uw=__float_as_uint(v.w)&0x7fffffffu;
    if ((ux>>10)==pre) atomicAdd(&hist[ux&1023u],1);
    if ((uy>>10)==pre) atomicAdd(&hist[uy&1023u],1);
    if ((uz>>10)==pre) atomicAdd(&hist[uz&1023u],1);
    if ((uw>>10)==pre) atomicAdd(&hist[uw&1023u],1);
  }
  __syncthreads();
  int2 f3=find_hist(hist,1024,r2,t,suf,sh2);
  if (t==0){
    ((unsigned*)(ws+OFF_T))[L]=(pre<<10)|(unsigned)f3.x;
    ws[OFF_WSC+L]=(ws[OFF_ONS+L]/(float)N)*sqrtf((float)KW_FAN[L])*0.5f;
  }
}

// ---------------- KW3: write blended weights (layer-specific layouts) ----------------
__global__ __launch_bounds__(256) void kw3_kernel(InPtrs in, float* __restrict__ ws){
  const int t=threadIdx.x, blk=blockIdx.x;
  const int L=KW_L[blk], s=KW_S[blk], nb=KW_NB[L];
  const int n4=KW_N[L]>>2;
  const int lo=(int)(((long long)n4*s)/nb), hi=(int)(((long long)n4*(s+1))/nb);
  const unsigned T=((const unsigned*)(ws+OFF_T))[L];
  const float4* sc4=(const float4*)in.sc[L];
  const float4* sg4=(const float4*)in.sg[L];
  const float4* on4=(const float4*)in.on[L];
  const float4* ze4=(const float4*)in.ze[L];
  float* wout=ws+(L==0?OFF_W1: L==2?OFF_W3 : OFF_W4);
  unsigned short* W2H=(unsigned short*)(ws+OFF_W2);
  unsigned short* W2L=W2H+9216;
  for (int i4=lo+t;i4<hi;i4+=256){
    float4 sv4=sc4[i4], g=sg4[i4], o=on4[i4], z=ze4[i4];
    float sv[4]={sv4.x,sv4.y,sv4.z,sv4.w}, gv[4]={g.x,g.y,g.z,g.w};
    float ov[4]={o.x,o.y,o.z,o.w}, zv[4]={z.x,z.y,z.z,z.w};
    #pragma unroll
    for (int j=0;j<4;++j){
      int i=i4*4+j;
      unsigned u=__float_as_uint(sv[j])&0x7fffffffu;
      float w=gv[j]*((u>=T)? ov[j] : zv[j]);
      if (L==1){
        int oc=i/576; int r=i-oc*576; int ic=r/9; int kp=r-ic*9;
        int o2=oc*576 + kp*64 + ic;
        unsigned short hb=f2bf(w);
        float lo2=w-__uint_as_float((unsigned)hb<<16);
        W2H[o2]=hb; W2L[o2]=f2bf(lo2);
      } else {
        int o2;
        if (L==0) o2=i;
        else if (L==2){ int oc=i/400; int kk=i-oc*400; o2=kk*128+oc; }
        else o2=i;
        wout[o2]=w;
      }
    }
  }
}

// ---------------- KB: conv1 (recomputed, 4 img/block) -> per-channel BN1 stats partials ----------------
__global__ __launch_bounds__(256,4) void kb_kernel(InPtrs in, const float* __restrict__ wsr, float* __restrict__ wsw){
  const int t=threadIdx.x, blk=blockIdx.x;
  __shared__ __align__(16) float qxs[224];
  const float* pooled=wsr+OFF_POOLED;
  const unsigned* U=(const unsigned*)(wsr+OFF_GMM);
  const float mn0=fdec(U[0]);
  const float mx0=fdec(U[1]);
  const float lvf=(float)((1<<in.qb[0])-1);
  const float s0=(mx0-mn0)/lvf;
  const float inv_s0=1.0f/s0;
  const float zp0=floorf(mn0/s0);
  const float inv_s1w=1.0f/wsr[OFF_WSC+0];
  const int c=t>>2, q=t&3;
  float w[9];
  #pragma unroll
  for (int j=0;j<9;++j) w[j]=wsr[OFF_W1+c*9+j];
  float sum=0.f,sq=0.f,vmn=3.4e38f,vmx=-3.4e38f;
  #pragma unroll 1
  for (int ii=0;ii<4;++ii){
    const int b=blk*4+ii;
    __syncthreads();
    for (int i=t;i<224;i+=256){
      int row=i>>4,col=i&15;
      float v=0.f;
      if (col<14){ float xx=pooled[b*196+row*14+col]; v=(rintf((xx-mn0)*inv_s0)+zp0)*s0; }
      qxs[i]=v;
    }
    __syncthreads();
    float rA[16],rB[16],rC[16];
    const int y0=q*3;
    loadrow16(qxs+y0*16,rA);
    loadrow16(qxs+(y0+1)*16,rB);
    loadrow16(qxs+(y0+2)*16,rC); c1row_stat(rA,rB,rC,w,inv_s1w,sum,sq,vmn,vmx);
    loadrow16(qxs+(y0+3)*16,rA); c1row_stat(rB,rC,rA,w,inv_s1w,sum,sq,vmn,vmx);
    loadrow16(qxs+(y0+4)*16,rB); c1row_stat(rC,rA,rB,w,inv_s1w,sum,sq,vmn,vmx);
  }
  #pragma unroll
  for (int d=1;d<4;d<<=1){
    sum+=__shfl_xor(sum,d);
    sq +=__shfl_xor(sq,d);
    vmn=fminf(vmn,__shfl_xor(vmn,d));
    vmx=fmaxf(vmx,__shfl_xor(vmx,d));
  }
  if (q==0){
    float* p=wsw+OFF_ST1+((size_t)c*NBB+blk)*4;
    p[0]=sum; p[1]=sq; p[2]=vmn; p[3]=vmx;
  }
}

// ---------------- kstat: per-channel partial reduce -> {mean, sd, tmin, tmax} + global tmin/tmax ----------------
__global__ __launch_bounds__(256) void kstat_kernel(const float* __restrict__ wsr, float* __restrict__ wsw,
                                                    unsigned long long inoff, int nparts, float Nf,
                                                    unsigned long long outoff, int mmslot){
  const int c=blockIdx.x, t=threadIdx.x;
  __shared__ float red[256];
  const float* p=wsr+inoff+(size_t)c*nparts*4;
  float sum=0.f,sq=0.f,mn=3.4e38f,mx=-3.4e38f;
  for (int i=t;i<nparts;i+=256){
    sum+=p[i*4]; sq+=p[i*4+1];
    mn=fminf(mn,p[i*4+2]); mx=fmaxf(mx,p[i*4+3]);
  }
  float S=blk_sum(sum,red,t);
  float Q=blk_sum(sq,red,t);
  float MN=blk_min(mn,red,t);
  float MX=blk_max(mx,red,t);
  if (t==0){
    float mean=S/Nf;
    float var=fmaxf(Q/Nf-mean*mean,0.f);
    float sd=sqrtf(var+1e-5f);
    float* o=wsw+outoff+c*4;
    float tmn=(MN-mean)/sd, tmx=(MX-mean)/sd;
    o[0]=mean; o[1]=sd; o[2]=tmn; o[3]=tmx;
    unsigned* U=(unsigned*)(wsw+OFF_GMM);
    atomicMin(&U[mmslot],fenc(tmn));
    atomicMax(&U[mmslot+1],fenc(tmx));
  }
}

// ---------------- KC: fused conv1->bn1/relu/quant->conv2(MFMA)->pool ----------------
// 4 img/block SEQUENTIAL, software-pipelined: phase1 = conv1(i) + pool(i-1) + qxs-prefetch(i+1),
// phase2 = conv2(i). 2 barriers/img. 1024 blocks = 4/CU -> whole grid resident, no generation
// turnover (R6 falsified register-starvation; this tests the serial-chain/generation theory).
__global__ __launch_bounds__(256,4) void kc_kernel(InPtrs in, const float* __restrict__ wsr, float* __restrict__ wsw){
  const int t=threadIdx.x, blk=blockIdx.x;
  __shared__ __align__(16) float qxs[2][224];           // double-buffered quantized input
  __shared__ __align__(16) unsigned short actA[144*72]; // [cell][72: 64 ch + 8 pad] bf16 codes (20.7 KB)
  __shared__ __align__(16) float c2s[1600];             // [oc][100] conv2 out (separate, no alias)
  __shared__ float sA[64], sB[64];
  __shared__ float stsum[16], stsq[16];
  __shared__ unsigned stmn[16], stmx[16];
  const float* pooled=wsr+OFF_POOLED;
  const unsigned* U=(const unsigned*)(wsr+OFF_GMM);
  const float mn0=fdec(U[0]);
  const float mx0=fdec(U[1]);
  const float rmn=fdec(U[2]);
  const float rmx=fdec(U[3]);
  const float lvf=(float)((1<<in.qb[0])-1);
  const float s0=(mx0-mn0)/lvf, inv_s0=1.0f/s0, zp0=floorf(mn0/s0);
  const float s1w=wsr[OFF_WSC+0], s2w=wsr[OFF_WSC+1];
  const float s2=(fmaxf(rmx,0.f)-fmaxf(rmn,0.f))/lvf;
  const float inv_s2=1.0f/s2;
  const float g2=s2/s2w;
  const int b0=blk*4;
  if (t<64){
    float m=wsr[OFF_BN1+t*4], sd=wsr[OFF_BN1+t*4+1];
    sA[t]=1.0f/(s1w*sd);
    sB[t]=-m/sd;
  }
  if (t<16){ stsum[t]=0.f; stsq[t]=0.f; stmn[t]=0xFFFFFFFFu; stmx[t]=0u; }
  // img0 input
  if (t<224){
    int row=t>>4, col=t&15;
    float v=0.f;
    if (col<14){ float xx=pooled[(size_t)b0*196+row*14+col]; v=(rintf((xx-mn0)*inv_s0)+zp0)*s0; }
    qxs[0][t]=v;
  }
  __syncthreads();

  const int part=t>>6, ch=t&63;          // conv1 role
  const int wv=t>>6, lane=t&63;          // conv2 role
  const int oc=lane&15, quad=lane>>4;
  float w1r[9];
  #pragma unroll
  for (int j=0;j<9;++j) w1r[j]=wsr[OFF_W1+ch*9+j];
  const float Ac=sA[ch], Bc=sB[ch];
  const unsigned short* W2H=(const unsigned short*)(wsr+OFF_W2);
  const unsigned short* W2L=W2H+9216;
  const int boff=oc*576+quad*8;
  const int nT=(wv<3)?2:1;
  int abase[2];
  #pragma unroll
  for (int i=0;i<2;++i){
    int tau=wv+i*4;
    int posb=tau*16+(lane&15);
    int pc=posb>99?99:posb;
    int py=pc/10, px=pc-py*10;
    abase[i]=(py*12+px)*72+quad*8;
  }

  #pragma unroll 1
  for (int img=0; img<4; ++img){
    const int cur=img&1;
    // ---- phase 1: conv1(img) -> actA ; prefetch qxs for img+1 ; pool(img-1) ----
    {
      const float* qx=qxs[cur];
      float rA[16],rB[16],rC[16];
      const int y0=part*3;
      loadrow16(qx+y0*16,rA);
      loadrow16(qx+(y0+1)*16,rB);
      loadrow16(qx+(y0+2)*16,rC); c1row1(rA,rB,rC,w1r,Ac,Bc,inv_s2,lvf,y0+0,ch,actA);
      loadrow16(qx+(y0+3)*16,rA); c1row1(rB,rC,rA,w1r,Ac,Bc,inv_s2,lvf,y0+1,ch,actA);
      loadrow16(qx+(y0+4)*16,rB); c1row1(rC,rA,rB,w1r,Ac,Bc,inv_s2,lvf,y0+2,ch,actA);
    }
    if (img<3 && t<224){
      int row=t>>4, col=t&15;
      float v=0.f;
      if (col<14){ float xx=pooled[(size_t)(b0+img+1)*196+row*14+col]; v=(rintf((xx-mn0)*inv_s0)+zp0)*s0; }
      qxs[cur^1][t]=v;
    }
    if (img>0){
      for (int i=t;i<400;i+=256){
        int chh=i/25, pp=i-chh*25;
        int py=pp/5, px=pp-py*5;
        const float* cc=c2s+chh*100;
        int base=py*20+px*2;
        float v=fmaxf(fmaxf(cc[base],cc[base+1]),fmaxf(cc[base+10],cc[base+11]));
        wsw[OFF_Y2P+(size_t)(b0+img-1)*400+i]=v;
        atomicAdd(&stsum[chh],v);
        atomicAdd(&stsq[chh],v*v);
        atomicMin(&stmn[chh],fenc(v));
        atomicMax(&stmx[chh],fenc(v));
      }
    }
    __syncthreads();
    // ---- phase 2: conv2(img) via MFMA: actA -> c2s ----
    {
      f32x4 acc[2];
      acc[0]=(f32x4){0.f,0.f,0.f,0.f};
      acc[1]=(f32x4){0.f,0.f,0.f,0.f};
      #pragma unroll
      for (int kykx=0;kykx<9;++kykx){
        const int kb=kykx*64;
        const int co=((kykx/3)*12+(kykx%3))*72;
        #pragma unroll
        for (int s=0;s<2;++s){
          bf16x8 bh=*(const bf16x8*)(W2H+boff+kb+s*32);
          bf16x8 bl=*(const bf16x8*)(W2L+boff+kb+s*32);
          #pragma unroll
          for (int i=0;i<2;++i){
            if (i<nT){
              bf16x8 a=*(const bf16x8*)(actA+abase[i]+co+s*32);
              acc[i]=__builtin_amdgcn_mfma_f32_16x16x32_bf16(a,bh,acc[i],0,0,0);
              acc[i]=__builtin_amdgcn_mfma_f32_16x16x32_bf16(a,bl,acc[i],0,0,0);
            }
          }
        }
      }
      // C layout: col(oc)=lane&15, row(pos-in-tile)=quad*4+reg
      #pragma unroll
      for (int i=0;i<2;++i){
        if (i<nT){
          int pos4=(wv+i*4)*16+quad*4;
          if (pos4<100){
            float4* dst=(float4*)&c2s[oc*100+pos4];
            *dst=make_float4(acc[i].x*g2,acc[i].y*g2,acc[i].z*g2,acc[i].w*g2);
          }
        }
      }
    }
    __syncthreads();
  }
  // ---- final pool (img 3) ----
  for (int i=t;i<400;i+=256){
    int chh=i/25, pp=i-chh*25;
    int py=pp/5, px=pp-py*5;
    const float* cc=c2s+chh*100;
    int base=py*20+px*2;
    float v=fmaxf(fmaxf(cc[base],cc[base+1]),fmaxf(cc[base+10],cc[base+11]));
    wsw[OFF_Y2P+(size_t)(b0+3)*400+i]=v;
    atomicAdd(&stsum[chh],v);
    atomicAdd(&stsq[chh],v*v);
    atomicMin(&stmn[chh],fenc(v));
    atomicMax(&stmx[chh],fenc(v));
  }
  __syncthreads();
  if (t<16){
    float* p=wsw+OFF_ST2+((size_t)t*NBC+blk)*4;
    p[0]=stsum[t]; p[1]=stsq[t]; p[2]=fdec(stmn[t]); p[3]=fdec(stmx[t]);
  }
}

// ---------------- KE: bn2/relu/quant -> fc1 -> relu, 8 img/block (2 img/wave) ----------------
__global__ __launch_bounds__(256) void ke_kernel(InPtrs in, const float* __restrict__ wsr, float* __restrict__ wsw){
  const int t=threadIdx.x, blk=blockIdx.x;
  __shared__ __align__(16) float xs[3200];   // 8 img x 400
  __shared__ float sm[16], sisd[16];
  const unsigned* U=(const unsigned*)(wsr+OFF_GMM);
  const float lvf=(float)((1<<in.qb[0])-1);
  const float rmn=fdec(U[4]);
  const float rmx=fdec(U[5]);
  if (t<16){ sm[t]=wsr[OFF_BN2+t*4]; sisd[t]=1.0f/wsr[OFF_BN2+t*4+1]; }
  const float s3=(fmaxf(rmx,0.f)-fmaxf(rmn,0.f))/lvf;
  const float inv_s3=1.0f/s3;
  const float inv_s3w=1.0f/wsr[OFF_WSC+2];
  const int b0=blk*8;
  __syncthreads();
  for (int i=t;i<3200;i+=256){
    int img=i/400, k=i-img*400;
    int ch=k/25;
    float y=wsr[OFF_Y2P+(size_t)(b0+img)*400+k];
    float bn=(y-sm[ch])*sisd[ch];
    float r=fmaxf(bn,0.f);
    xs[i]=fminf(rintf(r*inv_s3),lvf)*s3;
  }
  __syncthreads();
  const int w=t>>6, lane=t&63;
  const float* xA=xs+(w*2)*400;
  const float* xB=xs+(w*2+1)*400;
  const float* w3=wsr+OFF_W3;
  float aA0=0.f,aA1=0.f,aB0=0.f,aB1=0.f;
  #pragma unroll 2
  for (int k=0;k<400;k+=4){
    float4 va=*(const float4*)(xA+k);
    float4 vb=*(const float4*)(xB+k);
    float2 w0=*(const float2*)(w3+(k+0)*128+lane*2);
    float2 w1=*(const float2*)(w3+(k+1)*128+lane*2);
    float2 w2=*(const float2*)(w3+(k+2)*128+lane*2);
    float2 wv3=*(const float2*)(w3+(k+3)*128+lane*2);
    aA0=fmaf(va.x,w0.x,aA0); aA1=fmaf(va.x,w0.y,aA1);
    aB0=fmaf(vb.x,w0.x,aB0); aB1=fmaf(vb.x,w0.y,aB1);
    aA0=fmaf(va.y,w1.x,aA0); aA1=fmaf(va.y,w1.y,aA1);
    aB0=fmaf(vb.y,w1.x,aB0); aB1=fmaf(vb.y,w1.y,aB1);
    aA0=fmaf(va.z,w2.x,aA0); aA1=fmaf(va.z,w2.y,aA1);
    aB0=fmaf(vb.z,w2.x,aB0); aB1=fmaf(vb.z,w2.y,aB1);
    aA0=fmaf(va.w,wv3.x,aA0); aA1=fmaf(va.w,wv3.y,aA1);
    aB0=fmaf(vb.w,wv3.x,aB0); aB1=fmaf(vb.w,wv3.y,aB1);
  }
  float hA0=fmaxf(aA0*inv_s3w,0.f), hA1=fmaxf(aA1*inv_s3w,0.f);
  float hB0=fmaxf(aB0*inv_s3w,0.f), hB1=fmaxf(aB1*inv_s3w,0.f);
  *(float2*)(wsw+OFF_H3+(size_t)(b0+w*2)*128+lane*2)=make_float2(hA0,hA1);
  *(float2*)(wsw+OFF_H3+(size_t)(b0+w*2+1)*128+lane*2)=make_float2(hB0,hB1);
  float hmn=fminf(fminf(hA0,hA1),fminf(hB0,hB1));
  float hmx=fmaxf(fmaxf(hA0,hA1),fmaxf(hB0,hB1));
  #pragma unroll
  for (int d=1;d<64;d<<=1){
    hmn=fminf(hmn,__shfl_xor(hmn,d));
    hmx=fmaxf(hmx,__shfl_xor(hmx,d));
  }
  if (lane==0){
    unsigned* Uw=(unsigned*)(wsw+OFF_GMM);
    atomicMin(&Uw[6],fenc(hmn));
    atomicMax(&Uw[7],fenc(hmx));
  }
}

// ---------------- KF: quant -> fc2 -> log_softmax; 64 rows/block, 4 lanes/row ----------------
__global__ __launch_bounds__(256) void kf_kernel(InPtrs in, const float* __restrict__ wsr, float* __restrict__ out){
  const int t=threadIdx.x, blk=blockIdx.x;
  __shared__ float w4s[1280];
  const unsigned* U=(const unsigned*)(wsr+OFF_GMM);
  const float lvf=(float)((1<<in.qb[0])-1);
  const float hmn=fdec(U[6]);
  const float hmx=fdec(U[7]);
  for (int i=t;i<1280;i+=256) w4s[i]=wsr[OFF_W4+i];
  const float s4=(hmx-hmn)/lvf;
  const float inv_s4=1.0f/s4;
  const float inv_s4w=1.0f/wsr[OFF_WSC+3];
  __syncthreads();
  const int row=blk*64+(t>>2), l4=t&3;
  const float4* hr4=(const float4*)(wsr+OFF_H3+(size_t)row*128);
  float acc[10];
  #pragma unroll
  for (int j=0;j<10;++j) acc[j]=0.f;
  #pragma unroll 2
  for (int j=0;j<8;++j){
    float4 v=hr4[l4*8+j];
    int kb=(l4*8+j)*4;
    float q0=fminf(rintf(v.x*inv_s4),lvf)*s4;
    float q1=fminf(rintf(v.y*inv_s4),lvf)*s4;
    float q2=fminf(rintf(v.z*inv_s4),lvf)*s4;
    float q3=fminf(rintf(v.w*inv_s4),lvf)*s4;
    #pragma unroll
    for (int o=0;o<10;++o){
      const float* wr=w4s+o*128+kb;
      acc[o]=fmaf(q0,wr[0],acc[o]);
      acc[o]=fmaf(q1,wr[1],acc[o]);
      acc[o]=fmaf(q2,wr[2],acc[o]);
      acc[o]=fmaf(q3,wr[3],acc[o]);
    }
  }
  #pragma unroll
  for (int o=0;o<10;++o){
    acc[o]+=__shfl_xor(acc[o],1);
    acc[o]+=__shfl_xor(acc[o],2);
  }
  if (l4==0){
    float mx=-3.4e38f;
    #pragma unroll
    for (int o=0;o<10;++o){ acc[o]*=inv_s4w; mx=fmaxf(mx,acc[o]); }
    float se=0.f;
    #pragma unroll
    for (int o=0;o<10;++o) se+=expf(acc[o]-mx);
    const float ls=logf(se);
    #pragma unroll
    for (int o=0;o<10;++o) out[row*10+o]=acc[o]-mx-ls;
  }
}

extern "C" void kernel_launch(void* const* d_in, const int* in_sizes, int n_in,
                              void* d_out, int out_size, void* d_ws, size_t ws_size,
                              hipStream_t stream){
  (void)in_sizes; (void)n_in; (void)out_size; (void)ws_size;
  InPtrs P;
  P.x=(const float*)d_in[0];
  for (int l=0;l<4;++l){
    P.sc[l]=(const float*)d_in[1+l*4];
    P.sg[l]=(const float*)d_in[2+l*4];
    P.on[l]=(const float*)d_in[3+l*4];
    P.ze[l]=(const float*)d_in[4+l*4];
  }
  P.qb=(const int*)d_in[17];
  float* ws=(float*)d_ws;

  hipLaunchKernelGGL(ka_kernel,  dim3(NBA), dim3(256),  0, stream, P, ws);
  hipLaunchKernelGGL(kw1_kernel, dim3(NBW), dim3(256),  0, stream, P, ws);
  hipLaunchKernelGGL(kw2_kernel, dim3(4),   dim3(1024), 0, stream, P, ws);
  hipLaunchKernelGGL(kw3_kernel, dim3(NBW), dim3(256),  0, stream, P, ws);
  hipLaunchKernelGGL(kb_kernel,  dim3(NBB), dim3(256),  0, stream, P, ws, ws);
  hipLaunchKernelGGL(kstat_kernel, dim3(64), dim3(256), 0, stream, ws, ws,
                     (unsigned long long)OFF_ST1, NBB, 4096.f*144.f, (unsigned long long)OFF_BN1, 2);
  hipLaunchKernelGGL(kc_kernel,  dim3(NBC), dim3(256),  0, stream, P, ws, ws);
  hipLaunchKernelGGL(kstat_kernel, dim3(16), dim3(256), 0, stream, ws, ws,
                     (unsigned long long)OFF_ST2, NBC, 4096.f*25.f, (unsigned long long)OFF_BN2, 4);
  hipLaunchKernelGGL(ke_kernel,  dim3(NBE), dim3(256),  0, stream, P, ws, ws);
  hipLaunchKernelGGL(kf_kernel,  dim3(64),  dim3(256),  0, stream, P, ws, (float*)d_out);
}

// Round 8
// 389.151 us; speedup vs baseline: 1.0313x; 1.0313x over previous
//
#include <hip/hip_runtime.h>
#include <hip/hip_bf16.h>
#include <math.h>

#define DEV __device__ __forceinline__

constexpr int BATCH = 4096;
constexpr int NBA = 512;    // pool blocks (ka also carries 16 hist blocks)
constexpr int NBB = 4096;   // conv1-stats blocks (1 img each, MFMA)
constexpr int NBC = 4096;   // fused conv blocks (1 img each)
constexpr int NBE = 512;    // fc1 blocks (8 img each)
constexpr int NBW = 16;     // hist slices

// workspace layout (float offsets)
constexpr size_t OFF_POOLED = 0;                            // 4096*196
constexpr size_t OFF_Y2P = OFF_POOLED + (size_t)BATCH*196;  // 4096*400
constexpr size_t OFF_ST1 = OFF_Y2P;                         // 64*4096*4 = 1048576 <= 1638400; consumed by kstat1 BEFORE kc writes Y2P
constexpr size_t OFF_H3  = OFF_Y2P + (size_t)BATCH*400;     // 4096*128
constexpr size_t OFF_ST2 = OFF_H3;                          // 16*4096*4 = 262144; consumed by kstat2 BEFORE ke writes H3
constexpr size_t OFF_W2  = OFF_H3 + (size_t)BATCH*128;      // W2 bf16 hi[9216]+lo[9216] u16, [oc][kykx*64+ic]
constexpr size_t OFF_W3  = OFF_W2 + 9216;                   // 51200 [k*128+oc]
constexpr size_t OFF_W4  = OFF_W3 + 51200;                  // 1280 [oc*128+k]
constexpr size_t OFF_WSC = OFF_W4 + 1280;                   // 4 layer scales
constexpr size_t OFF_BN1 = OFF_WSC + 4;                     // 64*4
constexpr size_t OFF_BN2 = OFF_BN1 + 256;                   // 16*4
constexpr size_t OFF_GMM = OFF_BN2 + 64;                    // 8 encoded slots (see below)
constexpr size_t OFF_ONS = OFF_GMM + 8;                     // 16 per-slice sum(hw_one)
constexpr size_t OFF_T   = OFF_ONS + 16;                    // 4 thresholds
constexpr size_t OFF_MMA = OFF_T + 4;                       // 512*2 pooled min/max partials
constexpr size_t OFF_HIST= OFF_MMA + 1024;                  // 16*2048 per-slice histograms
constexpr size_t OFF_W1M = OFF_HIST + 32768;                // W1 MFMA-B layout: hi 2048 u16 + lo 2048 u16 ([ocT][oc16][k32])
// GMM: [0]=pooled min [1]=pooled max [2]=bn1 tmin [3]=bn1 tmax [4]=bn2 tmin [5]=bn2 tmax [6]=fc1 min [7]=fc1 max

typedef __attribute__((ext_vector_type(8))) short bf16x8;
typedef __attribute__((ext_vector_type(4))) float f32x4;

struct InPtrs {
  const float* x;
  const float* sc[4];
  const float* sg[4];
  const float* on[4];
  const float* ze[4];
  const int* qb;
};

// hist-slice partition: 16 slices over 4 layers
__constant__ const int KW_L[16]  ={0,1,1,2,2,2,2,2,2,2,2,2,2,2,2,3};
__constant__ const int KW_S[16]  ={0,0,1,0,1,2,3,4,5,6,7,8,9,10,11,0};
__constant__ const int KW_NB[4]  ={1,2,12,1};
__constant__ const int KW_N[4]   ={576,9216,51200,1280};
__constant__ const int KW_FAN[4] ={9,576,400,128};
__constant__ const int KW_BW0[4] ={0,1,3,15};
__constant__ const int KW_BW1[4] ={1,3,15,16};

DEV unsigned fenc(float f){ unsigned u=__float_as_uint(f); return (u&0x80000000u)? ~u : (u|0x80000000u); }
DEV float fdec(unsigned e){ return __uint_as_float((e&0x80000000u)? (e&0x7fffffffu) : ~e); }
DEV unsigned short f2bf(float f){ unsigned u=__float_as_uint(f); return (unsigned short)((u + 0x7fffu + ((u>>16)&1u))>>16); }

DEV float blk_sum(float v, float* red, int t){
  red[t]=v; __syncthreads();
  for (int s=128;s>0;s>>=1){ if(t<s) red[t]+=red[t+s]; __syncthreads(); }
  float r=red[0]; __syncthreads();
  return r;
}
DEV float blk_min(float v, float* red, int t){
  red[t]=v; __syncthreads();
  for (int s=128;s>0;s>>=1){ if(t<s) red[t]=fminf(red[t],red[t+s]); __syncthreads(); }
  float r=red[0]; __syncthreads();
  return r;
}
DEV float blk_max(float v, float* red, int t){
  red[t]=v; __syncthreads();
  for (int s=128;s>0;s>>=1){ if(t<s) red[t]=fmaxf(red[t],red[t+s]); __syncthreads(); }
  float r=red[0]; __syncthreads();
  return r;
}

// find bucket from top with 1024 threads; nbins<=2048
DEV int2 find_hist(const int* hist, int nbins, int kk, int t, int* suf, int* sh2){
  const int G=(nbins+1023)>>10;
  const int lo=t*G, hi=(lo+G<nbins)?(lo+G):nbins;
  int g=0;
  for (int b=lo;b<hi;++b) g+=hist[b];
  suf[t]=g; __syncthreads();
  #pragma unroll
  for (int s=1;s<1024;s<<=1){
    int add=(t+s<1024)?suf[t+s]:0;
    __syncthreads();
    suf[t]+=add;
    __syncthreads();
  }
  const int S=suf[t];
  const int Snext=(t<1023)?suf[t+1]:0;
  if (S>=kk && Snext<kk){
    int c2=Snext;
    for (int b=hi-1;b>=lo;--b){
      c2+=hist[b];
      if (c2>=kk){ sh2[0]=b; sh2[1]=kk-(c2-hist[b]); break; }
    }
  }
  __syncthreads();
  int2 r=make_int2(sh2[0],sh2[1]);
  __syncthreads();
  return r;
}

// ---------------- KA: blocks<512: 2x2 maxpool + per-block min/max partials.
//                    blocks 512..527: per-slice |score| histogram + sum(hw_one) partials. No races.
__global__ __launch_bounds__(256) void ka_kernel(InPtrs in, float* __restrict__ ws){
  const int t=threadIdx.x, blk=blockIdx.x;
  __shared__ int h[2048];
  __shared__ float red[256];
  if (blk<NBA){
    const float* x=in.x;
    float* pooled=ws+OFF_POOLED;
    float lmn=3.4e38f, lmx=-3.4e38f;
    for (int p=blk*256+t; p<BATCH*196; p+=NBA*256){
      int b=p/196, r=p-b*196;
      int oy=r/14, ox=r-oy*14;
      const float* px=x+b*784+oy*56+ox*2;
      float m=fmaxf(fmaxf(px[0],px[1]),fmaxf(px[28],px[29]));
      pooled[p]=m;
      lmn=fminf(lmn,m); lmx=fmaxf(lmx,m);
    }
    float bmn=blk_min(lmn,red,t);
    float bmx=blk_max(lmx,red,t);
    if (t==0){ ws[OFF_MMA+blk*2]=bmn; ws[OFF_MMA+blk*2+1]=bmx; }
  } else {
    const int bw=blk-NBA;
    const int L=KW_L[bw], s=KW_S[bw], nb=KW_NB[L];
    const int n4=KW_N[L]>>2;
    const int lo=(int)(((long long)n4*s)/nb), hi=(int)(((long long)n4*(s+1))/nb);
    const float4* sc4=(const float4*)in.sc[L];
    const float4* on4=(const float4*)in.on[L];
    for (int i=t;i<2048;i+=256) h[i]=0;
    __syncthreads();
    float onsum=0.f;
    for (int i=lo+t;i<hi;i+=256){
      float4 v=sc4[i];
      atomicAdd(&h[(__float_as_uint(v.x)&0x7fffffffu)>>20],1);
      atomicAdd(&h[(__float_as_uint(v.y)&0x7fffffffu)>>20],1);
      atomicAdd(&h[(__float_as_uint(v.z)&0x7fffffffu)>>20],1);
      atomicAdd(&h[(__float_as_uint(v.w)&0x7fffffffu)>>20],1);
      float4 o=on4[i];
      onsum+=(o.x+o.y)+(o.z+o.w);
    }
    __syncthreads();
    unsigned* GH=(unsigned*)(ws+OFF_HIST);
    for (int i=t;i<2048;i+=256) GH[bw*2048+i]=(unsigned)h[i];
    float S=blk_sum(onsum,red,t);
    if (t==0) ws[OFF_ONS+bw]=S;
  }
}

// ---------------- KW2: (block0: reduce pooled min/max, init GMM slots) + exact radix-select + weight writes
__global__ __launch_bounds__(1024) void kw2_kernel(InPtrs in, float* __restrict__ ws){
  const int t=threadIdx.x;
  const int L=blockIdx.x;
  __shared__ int hist[2048];
  __shared__ int suf[1024];
  __shared__ int sh2[2];
  __shared__ float redm[1024];
  __shared__ float redx[1024];

  if (L==0){
    // reduce the 512 pooled min/max partials -> U[0],U[1]; init U[2..7]
    float mn=3.4e38f,mx=-3.4e38f;
    if (t<NBA){ mn=ws[OFF_MMA+2*t]; mx=ws[OFF_MMA+2*t+1]; }
    redm[t]=mn; redx[t]=mx; __syncthreads();
    for (int s=512;s>0;s>>=1){
      if (t<s){ redm[t]=fminf(redm[t],redm[t+s]); redx[t]=fmaxf(redx[t],redx[t+s]); }
      __syncthreads();
    }
    unsigned* U=(unsigned*)(ws+OFF_GMM);
    if (t==0){ U[0]=fenc(redm[0]); U[1]=fenc(redx[0]); }
    if (t>=2 && t<8) U[t]=(t&1)? 0u : 0xFFFFFFFFu;   // min slots FFFF.., max slots 0
    __syncthreads();
  }

  const int N=KW_N[L];
  const int n4=N>>2;
  const int K=N>>1;
  const float4* sc4=(const float4*)in.sc[L];
  const unsigned* GH=(const unsigned*)(ws+OFF_HIST);
  // pass 1: merge slice histograms (bits [30:20])
  for (int i=t;i<2048;i+=1024){
    int s=0;
    for (int bw=KW_BW0[L]; bw<KW_BW1[L]; ++bw) s+=(int)GH[bw*2048+i];
    hist[i]=s;
  }
  __syncthreads();
  int2 f1=find_hist(hist,2048,K,t,suf,sh2);
  const unsigned b0=(unsigned)f1.x; const int r1=f1.y;

  // pass 2: bits [19:10]
  hist[t]=0;
  __syncthreads();
  for (int i=t;i<n4;i+=1024){
    float4 v=sc4[i];
    unsigned ux=__float_as_uint(v.x)&0x7fffffffu;
    unsigned uy=__float_as_uint(v.y)&0x7fffffffu;
    unsigned uz=__float_as_uint(v.z)&0x7fffffffu;
    unsigned uw=__float_as_uint(v.w)&0x7fffffffu;
    if ((ux>>20)==b0) atomicAdd(&hist[(ux>>10)&1023u],1);
    if ((uy>>20)==b0) atomicAdd(&hist[(uy>>10)&1023u],1);
    if ((uz>>20)==b0) atomicAdd(&hist[(uz>>10)&1023u],1);
    if ((uw>>20)==b0) atomicAdd(&hist[(uw>>10)&1023u],1);
  }
  __syncthreads();
  int2 f2=find_hist(hist,1024,r1,t,suf,sh2);
  const unsigned b1=(unsigned)f2.x; const int r2=f2.y;
  const unsigned pre=(b0<<10)|b1;

  // pass 3: bits [9:0]
  hist[t]=0;
  __syncthreads();
  for (int i=t;i<n4;i+=1024){
    float4 v=sc4[i];
    unsigned ux=__float_as_uint(v.x)&0x7fffffffu;
    unsigned uy=__float_as_uint(v.y)&0x7fffffffu;
    unsigned uz=__float_as_uint(v.z)&0x7fffffffu;
    unsigned uw=__float_as_uint(v.w)&0x7fffffffu;
    if ((ux>>10)==pre) atomicAdd(&hist[ux&1023u],1);
    if ((uy>>10)==pre) atomicAdd(&hist[uy&1023u],1);
    if ((uz>>10)==pre) atomicAdd(&hist[uz&1023u],1);
    if ((uw>>10)==pre) atomicAdd(&hist[uw&1023u],1);
  }
  __syncthreads();
  int2 f3=find_hist(hist,1024,r2,t,suf,sh2);
  const unsigned T=(pre<<10)|(unsigned)f3.x;
  if (t==0){
    ((unsigned*)(ws+OFF_T))[L]=T;
    float os=0.f;
    for (int bw=KW_BW0[L]; bw<KW_BW1[L]; ++bw) os+=ws[OFF_ONS+bw];
    ws[OFF_WSC+L]=(os/(float)N)*sqrtf((float)KW_FAN[L])*0.5f;
  }
  __syncthreads();

  // ---- weight writes (former kw3) ----
  unsigned short* W1MH=(unsigned short*)(ws+OFF_W1M);
  unsigned short* W1ML=W1MH+2048;
  if (L==0){
    unsigned* z=(unsigned*)W1MH;           // zero hi+lo (2048 dwords)
    if (t<1024){ z[t]=0u; z[t+1024]=0u; }
    __syncthreads();
  }
  const float4* sg4=(const float4*)in.sg[L];
  const float4* on4=(const float4*)in.on[L];
  const float4* ze4=(const float4*)in.ze[L];
  float* wout=ws+(L==2?OFF_W3:OFF_W4);
  unsigned short* W2H=(unsigned short*)(ws+OFF_W2);
  unsigned short* W2L=W2H+9216;
  for (int i4=t;i4<n4;i4+=1024){
    float4 sv4=sc4[i4], g=sg4[i4], o=on4[i4], z=ze4[i4];
    float sv[4]={sv4.x,sv4.y,sv4.z,sv4.w}, gv[4]={g.x,g.y,g.z,g.w};
    float ov[4]={o.x,o.y,o.z,o.w}, zv[4]={z.x,z.y,z.z,z.w};
    #pragma unroll
    for (int j=0;j<4;++j){
      int i=i4*4+j;
      unsigned u=__float_as_uint(sv[j])&0x7fffffffu;
      float w=gv[j]*((u>=T)? ov[j] : zv[j]);
      if (L==0){
        int oc=i/9; int k=i-oc*9;
        int o2=(oc>>4)*512+(oc&15)*32+k;       // [ocT][oc16][k32] MFMA-B layout
        unsigned short hb=f2bf(w);
        float lo2=w-__uint_as_float((unsigned)hb<<16);
        W1MH[o2]=hb; W1ML[o2]=f2bf(lo2);
      } else if (L==1){
        int oc=i/576; int r=i-oc*576; int ic=r/9; int kp=r-ic*9;
        int o2=oc*576 + kp*64 + ic;
        unsigned short hb=f2bf(w);
        float lo2=w-__uint_as_float((unsigned)hb<<16);
        W2H[o2]=hb; W2L[o2]=f2bf(lo2);
      } else {
        int o2;
        if (L==2){ int oc=i/400; int kk=i-oc*400; o2=kk*128+oc; }
        else o2=i;
        wout[o2]=w;
      }
    }
  }
}

// ---------------- KB: conv1 via MFMA -> per-channel BN1 stats partials (1 img/block) ----------------
__global__ __launch_bounds__(256) void kb_kernel(InPtrs in, const float* __restrict__ wsr, float* __restrict__ wsw){
  const int t=threadIdx.x, blk=blockIdx.x;
  __shared__ unsigned short qxs[256];            // 14x16 quantized-int bf16 codes
  __shared__ __align__(16) unsigned PAT[2880];   // patches [pos144][20 dwords = 40 u16, k0..31 used]
  __shared__ float xw[1024];                     // [wave4][ocT4][l16][4 stats]
  const float* pooled=wsr+OFF_POOLED;
  const unsigned* U=(const unsigned*)(wsr+OFF_GMM);
  const float mn0=fdec(U[0]);
  const float mx0=fdec(U[1]);
  const float lvf=(float)((1<<in.qb[0])-1);
  const float s0=(mx0-mn0)/lvf, inv_s0=1.0f/s0, zp0=floorf(mn0/s0);
  const float sv=s0/wsr[OFF_WSC+0];              // conv_int -> conv_float/s1w
  // stage quantized input as bf16 int codes
  if (t<224){
    int row=t>>4, col=t&15;
    float q=0.f;
    if (col<14){ float xx=pooled[(size_t)blk*196+row*14+col]; q=rintf((xx-mn0)*inv_s0)+zp0; }
    qxs[t]=(unsigned short)(__float_as_uint(q)>>16);
  }
  __syncthreads();
  // build patch matrix (K padded to 32 with zeros)
  for (int idx=t; idx<2304; idx+=256){
    int pos=idx>>4, kd=idx&15;
    int py=pos/12, px=pos-py*12;
    unsigned c0=0u,c1=0u;
    int k0=kd*2;
    if (k0<9){ int ky=k0/3,kx=k0-ky*3; c0=qxs[(py+ky)*16+px+kx]; }
    if (k0+1<9){ int k1=k0+1; int ky=k1/3,kx=k1-ky*3; c1=qxs[(py+ky)*16+px+kx]; }
    PAT[pos*20+kd]=c0|(c1<<16);
  }
  __syncthreads();
  // MFMA: 9 M-tiles over 4 waves
  {
    const int w=t>>6, lane=t&63;
    const int l15=lane&15, quad=lane>>4;
    const unsigned short* W1MH=(const unsigned short*)(wsr+OFF_W1M);
    const unsigned short* W1ML=W1MH+2048;
    const unsigned short* PATu=(const unsigned short*)PAT;
    #pragma unroll
    for (int ocT=0; ocT<4; ++ocT){
      bf16x8 bh=*(const bf16x8*)(W1MH+ocT*512+l15*32+quad*8);
      bf16x8 bl=*(const bf16x8*)(W1ML+ocT*512+l15*32+quad*8);
      float sum=0.f,sq=0.f,mn=3.4e38f,mx=-3.4e38f;
      for (int tl=w; tl<9; tl+=4){
        bf16x8 a=*(const bf16x8*)(PATu+(tl*16+l15)*40+quad*8);
        f32x4 acc=(f32x4){0.f,0.f,0.f,0.f};
        acc=__builtin_amdgcn_mfma_f32_16x16x32_bf16(a,bh,acc,0,0,0);
        acc=__builtin_amdgcn_mfma_f32_16x16x32_bf16(a,bl,acc,0,0,0);
        #pragma unroll
        for (int r=0;r<4;++r){
          float v=acc[r]*sv;
          sum+=v; sq=fmaf(v,v,sq); mn=fminf(mn,v); mx=fmaxf(mx,v);
        }
      }
      #pragma unroll
      for (int d=16;d<64;d<<=1){
        sum+=__shfl_xor(sum,d);
        sq +=__shfl_xor(sq,d);
        mn=fminf(mn,__shfl_xor(mn,d));
        mx=fmaxf(mx,__shfl_xor(mx,d));
      }
      if (quad==0){
        float* p=xw+((w*4+ocT)*16+l15)*4;
        p[0]=sum; p[1]=sq; p[2]=mn; p[3]=mx;
      }
    }
  }
  __syncthreads();
  if (t<64){
    float sum=0.f,sq=0.f,mn=3.4e38f,mx=-3.4e38f;
    #pragma unroll
    for (int w=0;w<4;++w){
      const float* p=xw+((w*4+(t>>4))*16+(t&15))*4;
      sum+=p[0]; sq+=p[1]; mn=fminf(mn,p[2]); mx=fmaxf(mx,p[3]);
    }
    float* p=wsw+OFF_ST1+((size_t)t*NBB+blk)*4;
    p[0]=sum; p[1]=sq; p[2]=mn; p[3]=mx;
  }
}

// ---------------- kstat: per-channel partial reduce -> {mean, sd, tmin, tmax} + global tmin/tmax ----------------
__global__ __launch_bounds__(256) void kstat_kernel(const float* __restrict__ wsr, float* __restrict__ wsw,
                                                    unsigned long long inoff, int nparts, float Nf,
                                                    unsigned long long outoff, int mmslot){
  const int c=blockIdx.x, t=threadIdx.x;
  __shared__ float red[256];
  const float* p=wsr+inoff+(size_t)c*nparts*4;
  float sum=0.f,sq=0.f,mn=3.4e38f,mx=-3.4e38f;
  for (int i=t;i<nparts;i+=256){
    sum+=p[i*4]; sq+=p[i*4+1];
    mn=fminf(mn,p[i*4+2]); mx=fmaxf(mx,p[i*4+3]);
  }
  float S=blk_sum(sum,red,t);
  float Q=blk_sum(sq,red,t);
  float MN=blk_min(mn,red,t);
  float MX=blk_max(mx,red,t);
  if (t==0){
    float mean=S/Nf;
    float var=fmaxf(Q/Nf-mean*mean,0.f);
    float sd=sqrtf(var+1e-5f);
    float* o=wsw+outoff+c*4;
    float tmn=(MN-mean)/sd, tmx=(MX-mean)/sd;
    o[0]=mean; o[1]=sd; o[2]=tmn; o[3]=tmx;
    unsigned* U=(unsigned*)(wsw+OFF_GMM);
    atomicMin(&U[mmslot],fenc(tmn));
    atomicMax(&U[mmslot+1],fenc(tmx));
  }
}

// ---------------- KC: conv1(MFMA)->bn1/relu/quant->conv2(MFMA)->pool, 1 img/block ----------------
__global__ __launch_bounds__(256) void kc_kernel(InPtrs in, const float* __restrict__ wsr, float* __restrict__ wsw){
  const int t=threadIdx.x, blk=blockIdx.x;
  __shared__ unsigned short qxs[256];
  __shared__ __align__(16) unsigned PAT[2880];           // patches; aliased by c2s after conv1
  __shared__ __align__(16) unsigned short actA[144*72];  // [cell][72: 64 ch + 8 pad] bf16 codes
  __shared__ float sA2[64], sB2[64];
  __shared__ float stsum[16], stsq[16];
  __shared__ unsigned stmn[16], stmx[16];
  float* c2s=(float*)PAT;                                // [oc16][100] conv2 out (6400B <= 11520B)
  const float* pooled=wsr+OFF_POOLED;
  const unsigned* U=(const unsigned*)(wsr+OFF_GMM);
  const float mn0=fdec(U[0]);
  const float mx0=fdec(U[1]);
  const float rmn=fdec(U[2]);
  const float rmx=fdec(U[3]);
  const float lvf=(float)((1<<in.qb[0])-1);
  const float s0=(mx0-mn0)/lvf, inv_s0=1.0f/s0, zp0=floorf(mn0/s0);
  const float s1w=wsr[OFF_WSC+0], s2w=wsr[OFF_WSC+1];
  const float s2=(fmaxf(rmx,0.f)-fmaxf(rmn,0.f))/lvf;
  const float inv_s2=1.0f/s2;
  const float g2=s2/s2w;
  if (t<64){
    float m=wsr[OFF_BN1+t*4], sd=wsr[OFF_BN1+t*4+1];
    sA2[t]=s0/(s1w*sd);        // applied to integer conv accumulator
    sB2[t]=-m/sd;
  }
  if (t<16){ stsum[t]=0.f; stsq[t]=0.f; stmn[t]=0xFFFFFFFFu; stmx[t]=0u; }
  if (t<224){
    int row=t>>4, col=t&15;
    float q=0.f;
    if (col<14){ float xx=pooled[(size_t)blk*196+row*14+col]; q=rintf((xx-mn0)*inv_s0)+zp0; }
    qxs[t]=(unsigned short)(__float_as_uint(q)>>16);
  }
  __syncthreads();
  // patch build
  for (int idx=t; idx<2304; idx+=256){
    int pos=idx>>4, kd=idx&15;
    int py=pos/12, px=pos-py*12;
    unsigned c0=0u,c1=0u;
    int k0=kd*2;
    if (k0<9){ int ky=k0/3,kx=k0-ky*3; c0=qxs[(py+ky)*16+px+kx]; }
    if (k0+1<9){ int k1=k0+1; int ky=k1/3,kx=k1-ky*3; c1=qxs[(py+ky)*16+px+kx]; }
    PAT[pos*20+kd]=c0|(c1<<16);
  }
  __syncthreads();
  // conv1 MFMA + bn/relu/quant -> actA
  {
    const int w=t>>6, lane=t&63;
    const int l15=lane&15, quad=lane>>4;
    const unsigned short* W1MH=(const unsigned short*)(wsr+OFF_W1M);
    const unsigned short* W1ML=W1MH+2048;
    const unsigned short* PATu=(const unsigned short*)PAT;
    #pragma unroll
    for (int ocT=0; ocT<4; ++ocT){
      bf16x8 bh=*(const bf16x8*)(W1MH+ocT*512+l15*32+quad*8);
      bf16x8 bl=*(const bf16x8*)(W1ML+ocT*512+l15*32+quad*8);
      const int oc=ocT*16+l15;
      const float a2=sA2[oc], b2=sB2[oc];
      for (int tl=w; tl<9; tl+=4){
        bf16x8 a=*(const bf16x8*)(PATu+(tl*16+l15)*40+quad*8);
        f32x4 acc=(f32x4){0.f,0.f,0.f,0.f};
        acc=__builtin_amdgcn_mfma_f32_16x16x32_bf16(a,bh,acc,0,0,0);
        acc=__builtin_amdgcn_mfma_f32_16x16x32_bf16(a,bl,acc,0,0,0);
        #pragma unroll
        for (int r=0;r<4;++r){
          int pos=tl*16+quad*4+r;
          float f=fminf(rintf(fmaxf(fmaf(acc[r],a2,b2),0.f)*inv_s2),lvf);
          actA[pos*72+oc]=(unsigned short)(__float_as_uint(f)>>16);
        }
      }
    }
  }
  __syncthreads();
  // conv2 via MFMA (verified R6 code): 7 M-tiles of 16 positions; wave w gets tau=w, w+4
  {
    const int w=t>>6, lane=t&63;
    const int oc=lane&15, quad=lane>>4;
    const unsigned short* W2H=(const unsigned short*)(wsr+OFF_W2);
    const unsigned short* W2L=W2H+9216;
    const int boff=oc*576+quad*8;
    const int nT=(w<3)?2:1;
    int abase[2]; int taus[2];
    for (int i=0;i<nT;++i){
      int tau=w+i*4;
      int posb=tau*16+(lane&15);
      int pc=posb>99?99:posb;
      int py=pc/10, px=pc-py*10;
      abase[i]=(py*12+px)*72+quad*8;
      taus[i]=tau;
    }
    f32x4 acc[2];
    acc[0]=(f32x4){0.f,0.f,0.f,0.f};
    acc[1]=(f32x4){0.f,0.f,0.f,0.f};
    #pragma unroll 1
    for (int kykx=0;kykx<9;++kykx){
      const int kb=kykx*64;
      const int co=((kykx/3)*12+(kykx%3))*72;
      #pragma unroll
      for (int s=0;s<2;++s){
        bf16x8 bh=*(const bf16x8*)(W2H+boff+kb+s*32);
        bf16x8 bl=*(const bf16x8*)(W2L+boff+kb+s*32);
        #pragma unroll
        for (int i=0;i<2;++i){
          if (i<nT){
            bf16x8 a=*(const bf16x8*)(actA+abase[i]+co+s*32);
            acc[i]=__builtin_amdgcn_mfma_f32_16x16x32_bf16(a,bh,acc[i],0,0,0);
            acc[i]=__builtin_amdgcn_mfma_f32_16x16x32_bf16(a,bl,acc[i],0,0,0);
          }
        }
      }
    }
    __syncthreads();   // PAT reads done (conv1) + actA reads done -> safe to write c2s (aliases PAT)
    for (int i=0;i<nT;++i){
      int pos4=taus[i]*16+quad*4;
      if (pos4<100){
        float4* dst=(float4*)&c2s[oc*100+pos4];
        *dst=make_float4(acc[i].x*g2,acc[i].y*g2,acc[i].z*g2,acc[i].w*g2);
      }
    }
  }
  __syncthreads();
  // 2x2 maxpool + per-channel stats
  for (int i=t;i<400;i+=256){
    int ch=i/25, pp=i-ch*25;
    int py=pp/5, px=pp-py*5;
    const float* cc=c2s+ch*100;
    int base=py*20+px*2;
    float v=fmaxf(fmaxf(cc[base],cc[base+1]),fmaxf(cc[base+10],cc[base+11]));
    wsw[OFF_Y2P+(size_t)blk*400+i]=v;
    atomicAdd(&stsum[ch],v);
    atomicAdd(&stsq[ch],v*v);
    atomicMin(&stmn[ch],fenc(v));
    atomicMax(&stmx[ch],fenc(v));
  }
  __syncthreads();
  if (t<16){
    float* p=wsw+OFF_ST2+((size_t)t*NBC+blk)*4;
    p[0]=stsum[t]; p[1]=stsq[t]; p[2]=fdec(stmn[t]); p[3]=fdec(stmx[t]);
  }
}

// ---------------- KE: bn2/relu/quant -> fc1 -> relu, 8 img/block (2 img/wave) ----------------
__global__ __launch_bounds__(256) void ke_kernel(InPtrs in, const float* __restrict__ wsr, float* __restrict__ wsw){
  const int t=threadIdx.x, blk=blockIdx.x;
  __shared__ __align__(16) float xs[3200];   // 8 img x 400
  __shared__ float sm[16], sisd[16];
  const unsigned* U=(const unsigned*)(wsr+OFF_GMM);
  const float lvf=(float)((1<<in.qb[0])-1);
  const float rmn=fdec(U[4]);
  const float rmx=fdec(U[5]);
  if (t<16){ sm[t]=wsr[OFF_BN2+t*4]; sisd[t]=1.0f/wsr[OFF_BN2+t*4+1]; }
  const float s3=(fmaxf(rmx,0.f)-fmaxf(rmn,0.f))/lvf;
  const float inv_s3=1.0f/s3;
  const float inv_s3w=1.0f/wsr[OFF_WSC+2];
  const int b0=blk*8;
  __syncthreads();
  for (int i=t;i<3200;i+=256){
    int img=i/400, k=i-img*400;
    int ch=k/25;
    float y=wsr[OFF_Y2P+(size_t)(b0+img)*400+k];
    float bn=(y-sm[ch])*sisd[ch];
    float r=fmaxf(bn,0.f);
    xs[i]=fminf(rintf(r*inv_s3),lvf)*s3;
  }
  __syncthreads();
  const int w=t>>6, lane=t&63;
  const float* xA=xs+(w*2)*400;
  const float* xB=xs+(w*2+1)*400;
  const float* w3=wsr+OFF_W3;
  float aA0=0.f,aA1=0.f,aB0=0.f,aB1=0.f;
  #pragma unroll 2
  for (int k=0;k<400;k+=4){
    float4 va=*(const float4*)(xA+k);
    float4 vb=*(const float4*)(xB+k);
    float2 w0=*(const float2*)(w3+(k+0)*128+lane*2);
    float2 w1=*(const float2*)(w3+(k+1)*128+lane*2);
    float2 w2=*(const float2*)(w3+(k+2)*128+lane*2);
    float2 wv3=*(const float2*)(w3+(k+3)*128+lane*2);
    aA0=fmaf(va.x,w0.x,aA0); aA1=fmaf(va.x,w0.y,aA1);
    aB0=fmaf(vb.x,w0.x,aB0); aB1=fmaf(vb.x,w0.y,aB1);
    aA0=fmaf(va.y,w1.x,aA0); aA1=fmaf(va.y,w1.y,aA1);
    aB0=fmaf(vb.y,w1.x,aB0); aB1=fmaf(vb.y,w1.y,aB1);
    aA0=fmaf(va.z,w2.x,aA0); aA1=fmaf(va.z,w2.y,aA1);
    aB0=fmaf(vb.z,w2.x,aB0); aB1=fmaf(vb.z,w2.y,aB1);
    aA0=fmaf(va.w,wv3.x,aA0); aA1=fmaf(va.w,wv3.y,aA1);
    aB0=fmaf(vb.w,wv3.x,aB0); aB1=fmaf(vb.w,wv3.y,aB1);
  }
  float hA0=fmaxf(aA0*inv_s3w,0.f), hA1=fmaxf(aA1*inv_s3w,0.f);
  float hB0=fmaxf(aB0*inv_s3w,0.f), hB1=fmaxf(aB1*inv_s3w,0.f);
  *(float2*)(wsw+OFF_H3+(size_t)(b0+w*2)*128+lane*2)=make_float2(hA0,hA1);
  *(float2*)(wsw+OFF_H3+(size_t)(b0+w*2+1)*128+lane*2)=make_float2(hB0,hB1);
  float hmn=fminf(fminf(hA0,hA1),fminf(hB0,hB1));
  float hmx=fmaxf(fmaxf(hA0,hA1),fmaxf(hB0,hB1));
  #pragma unroll
  for (int d=1;d<64;d<<=1){
    hmn=fminf(hmn,__shfl_xor(hmn,d));
    hmx=fmaxf(hmx,__shfl_xor(hmx,d));
  }
  if (lane==0){
    unsigned* Uw=(unsigned*)(wsw+OFF_GMM);
    atomicMin(&Uw[6],fenc(hmn));
    atomicMax(&Uw[7],fenc(hmx));
  }
}

// ---------------- KF: quant -> fc2 -> log_softmax; 64 rows/block, 4 lanes/row ----------------
__global__ __launch_bounds__(256) void kf_kernel(InPtrs in, const float* __restrict__ wsr, float* __restrict__ out){
  const int t=threadIdx.x, blk=blockIdx.x;
  __shared__ float w4s[1280];
  const unsigned* U=(const unsigned*)(wsr+OFF_GMM);
  const float lvf=(float)((1<<in.qb[0])-1);
  const float hmn=fdec(U[6]);
  const float hmx=fdec(U[7]);
  for (int i=t;i<1280;i+=256) w4s[i]=wsr[OFF_W4+i];
  const float s4=(hmx-hmn)/lvf;
  const float inv_s4=1.0f/s4;
  const float inv_s4w=1.0f/wsr[OFF_WSC+3];
  __syncthreads();
  const int row=blk*64+(t>>2), l4=t&3;
  const float4* hr4=(const float4*)(wsr+OFF_H3+(size_t)row*128);
  float acc[10];
  #pragma unroll
  for (int j=0;j<10;++j) acc[j]=0.f;
  #pragma unroll 2
  for (int j=0;j<8;++j){
    float4 v=hr4[l4*8+j];
    int kb=(l4*8+j)*4;
    float q0=fminf(rintf(v.x*inv_s4),lvf)*s4;
    float q1=fminf(rintf(v.y*inv_s4),lvf)*s4;
    float q2=fminf(rintf(v.z*inv_s4),lvf)*s4;
    float q3=fminf(rintf(v.w*inv_s4),lvf)*s4;
    #pragma unroll
    for (int o=0;o<10;++o){
      const float* wr=w4s+o*128+kb;
      acc[o]=fmaf(q0,wr[0],acc[o]);
      acc[o]=fmaf(q1,wr[1],acc[o]);
      acc[o]=fmaf(q2,wr[2],acc[o]);
      acc[o]=fmaf(q3,wr[3],acc[o]);
    }
  }
  #pragma unroll
  for (int o=0;o<10;++o){
    acc[o]+=__shfl_xor(acc[o],1);
    acc[o]+=__shfl_xor(acc[o],2);
  }
  if (l4==0){
    float mx=-3.4e38f;
    #pragma unroll
    for (int o=0;o<10;++o){ acc[o]*=inv_s4w; mx=fmaxf(mx,acc[o]); }
    float se=0.f;
    #pragma unroll
    for (int o=0;o<10;++o) se+=expf(acc[o]-mx);
    const float ls=logf(se);
    #pragma unroll
    for (int o=0;o<10;++o) out[row*10+o]=acc[o]-mx-ls;
  }
}

extern "C" void kernel_launch(void* const* d_in, const int* in_sizes, int n_in,
                              void* d_out, int out_size, void* d_ws, size_t ws_size,
                              hipStream_t stream){
  (void)in_sizes; (void)n_in; (void)out_size; (void)ws_size;
  InPtrs P;
  P.x=(const float*)d_in[0];
  for (int l=0;l<4;++l){
    P.sc[l]=(const float*)d_in[1+l*4];
    P.sg[l]=(const float*)d_in[2+l*4];
    P.on[l]=(const float*)d_in[3+l*4];
    P.ze[l]=(const float*)d_in[4+l*4];
  }
  P.qb=(const int*)d_in[17];
  float* ws=(float*)d_ws;

  hipLaunchKernelGGL(ka_kernel,  dim3(NBA+NBW), dim3(256),  0, stream, P, ws);
  hipLaunchKernelGGL(kw2_kernel, dim3(4),       dim3(1024), 0, stream, P, ws);
  hipLaunchKernelGGL(kb_kernel,  dim3(NBB),     dim3(256),  0, stream, P, ws, ws);
  hipLaunchKernelGGL(kstat_kernel, dim3(64), dim3(256), 0, stream, ws, ws,
                     (unsigned long long)OFF_ST1, NBB, 4096.f*144.f, (unsigned long long)OFF_BN1, 2);
  hipLaunchKernelGGL(kc_kernel,  dim3(NBC),     dim3(256),  0, stream, P, ws, ws);
  hipLaunchKernelGGL(kstat_kernel, dim3(16), dim3(256), 0, stream, ws, ws,
                     (unsigned long long)OFF_ST2, NBC, 4096.f*25.f, (unsigned long long)OFF_BN2, 4);
  hipLaunchKernelGGL(ke_kernel,  dim3(NBE),     dim3(256),  0, stream, P, ws, ws);
  hipLaunchKernelGGL(kf_kernel,  dim3(64),      dim3(256),  0, stream, P, ws, (float*)d_out);
}

// Round 9
// 355.938 us; speedup vs baseline: 1.1276x; 1.0933x over previous
//
#include <hip/hip_runtime.h>
#include <hip/hip_bf16.h>
#include <math.h>

#define DEV __device__ __forceinline__

constexpr int BATCH = 4096;
constexpr int NBA = 512;    // pool blocks (ka also carries 16 hist blocks)
constexpr int NBB = 4096;   // conv1-stats blocks (1 img each, MFMA)
constexpr int NBC = 4096;   // fused conv blocks (1 img each)
constexpr int NBE = 512;    // fc1 blocks (8 img each)
constexpr int NBW = 16;     // hist slices

// workspace layout (float offsets)
constexpr size_t OFF_POOLED = 0;                            // 4096*196
constexpr size_t OFF_Y2P = OFF_POOLED + (size_t)BATCH*196;  // 4096*400
constexpr size_t OFF_ST1 = OFF_Y2P;                         // 64*4096*4; consumed by kstat1 BEFORE kc writes Y2P
constexpr size_t OFF_H3  = OFF_Y2P + (size_t)BATCH*400;     // 4096*128
constexpr size_t OFF_ST2 = OFF_H3;                          // 16*4096*4; consumed by kstat2 BEFORE ke writes H3
constexpr size_t OFF_W2  = OFF_H3 + (size_t)BATCH*128;      // W2F u16[9][2][2][4][16][8] lane-linear (36864 B)
constexpr size_t OFF_W3  = OFF_W2 + 9216;                   // 51200 [k*128+oc]
constexpr size_t OFF_W4  = OFF_W3 + 51200;                  // 1280 [oc*128+k]
constexpr size_t OFF_WSC = OFF_W4 + 1280;                   // 4 layer scales
constexpr size_t OFF_BN1 = OFF_WSC + 4;                     // 64*4
constexpr size_t OFF_BN2 = OFF_BN1 + 256;                   // 16*4
constexpr size_t OFF_GMM = OFF_BN2 + 64;                    // 8 encoded slots (see below)
constexpr size_t OFF_ONS = OFF_GMM + 8;                     // 16 per-slice sum(hw_one)
constexpr size_t OFF_T   = OFF_ONS + 16;                    // 4 thresholds
constexpr size_t OFF_MMA = OFF_T + 4;                       // 512*2 pooled min/max partials
constexpr size_t OFF_HIST= OFF_MMA + 1024;                  // 16*2048 per-slice histograms
constexpr size_t OFF_W1M = OFF_HIST + 32768;                // W1F u16[4][2][4][16][8] lane-linear (8192 B)
// GMM: [0]=pooled min [1]=pooled max [2]=bn1 tmin [3]=bn1 tmax [4]=bn2 tmin [5]=bn2 tmax [6]=fc1 min [7]=fc1 max

typedef __attribute__((ext_vector_type(8))) short bf16x8;
typedef __attribute__((ext_vector_type(4))) float f32x4;

struct InPtrs {
  const float* x;
  const float* sc[4];
  const float* sg[4];
  const float* on[4];
  const float* ze[4];
  const int* qb;
};

// hist-slice partition: 16 slices over 4 layers
__constant__ const int KW_L[16]  ={0,1,1,2,2,2,2,2,2,2,2,2,2,2,2,3};
__constant__ const int KW_S[16]  ={0,0,1,0,1,2,3,4,5,6,7,8,9,10,11,0};
__constant__ const int KW_NB[4]  ={1,2,12,1};
__constant__ const int KW_N[4]   ={576,9216,51200,1280};
__constant__ const int KW_FAN[4] ={9,576,400,128};
__constant__ const int KW_BW0[4] ={0,1,3,15};
__constant__ const int KW_BW1[4] ={1,3,15,16};

DEV unsigned fenc(float f){ unsigned u=__float_as_uint(f); return (u&0x80000000u)? ~u : (u|0x80000000u); }
DEV float fdec(unsigned e){ return __uint_as_float((e&0x80000000u)? (e&0x7fffffffu) : ~e); }
DEV unsigned short f2bf(float f){ unsigned u=__float_as_uint(f); return (unsigned short)((u + 0x7fffu + ((u>>16)&1u))>>16); }

DEV float blk_sum(float v, float* red, int t){
  red[t]=v; __syncthreads();
  for (int s=128;s>0;s>>=1){ if(t<s) red[t]+=red[t+s]; __syncthreads(); }
  float r=red[0]; __syncthreads();
  return r;
}
DEV float blk_min(float v, float* red, int t){
  red[t]=v; __syncthreads();
  for (int s=128;s>0;s>>=1){ if(t<s) red[t]=fminf(red[t],red[t+s]); __syncthreads(); }
  float r=red[0]; __syncthreads();
  return r;
}
DEV float blk_max(float v, float* red, int t){
  red[t]=v; __syncthreads();
  for (int s=128;s>0;s>>=1){ if(t<s) red[t]=fmaxf(red[t],red[t+s]); __syncthreads(); }
  float r=red[0]; __syncthreads();
  return r;
}

// find bucket from top with 1024 threads; nbins<=2048
DEV int2 find_hist(const int* hist, int nbins, int kk, int t, int* suf, int* sh2){
  const int G=(nbins+1023)>>10;
  const int lo=t*G, hi=(lo+G<nbins)?(lo+G):nbins;
  int g=0;
  for (int b=lo;b<hi;++b) g+=hist[b];
  suf[t]=g; __syncthreads();
  #pragma unroll
  for (int s=1;s<1024;s<<=1){
    int add=(t+s<1024)?suf[t+s]:0;
    __syncthreads();
    suf[t]+=add;
    __syncthreads();
  }
  const int S=suf[t];
  const int Snext=(t<1023)?suf[t+1]:0;
  if (S>=kk && Snext<kk){
    int c2=Snext;
    for (int b=hi-1;b>=lo;--b){
      c2+=hist[b];
      if (c2>=kk){ sh2[0]=b; sh2[1]=kk-(c2-hist[b]); break; }
    }
  }
  __syncthreads();
  int2 r=make_int2(sh2[0],sh2[1]);
  __syncthreads();
  return r;
}

// ---------------- KA: blocks<512: 2x2 maxpool + per-block min/max partials.
//                    blocks 512..527: per-slice |score| histogram + sum(hw_one) partials.
__global__ __launch_bounds__(256) void ka_kernel(InPtrs in, float* __restrict__ ws){
  const int t=threadIdx.x, blk=blockIdx.x;
  __shared__ int h[2048];
  __shared__ float red[256];
  if (blk<NBA){
    const float* x=in.x;
    float* pooled=ws+OFF_POOLED;
    float lmn=3.4e38f, lmx=-3.4e38f;
    for (int p=blk*256+t; p<BATCH*196; p+=NBA*256){
      int b=p/196, r=p-b*196;
      int oy=r/14, ox=r-oy*14;
      const float* px=x+b*784+oy*56+ox*2;
      float m=fmaxf(fmaxf(px[0],px[1]),fmaxf(px[28],px[29]));
      pooled[p]=m;
      lmn=fminf(lmn,m); lmx=fmaxf(lmx,m);
    }
    float bmn=blk_min(lmn,red,t);
    float bmx=blk_max(lmx,red,t);
    if (t==0){ ws[OFF_MMA+blk*2]=bmn; ws[OFF_MMA+blk*2+1]=bmx; }
  } else {
    const int bw=blk-NBA;
    const int L=KW_L[bw], s=KW_S[bw], nb=KW_NB[L];
    const int n4=KW_N[L]>>2;
    const int lo=(int)(((long long)n4*s)/nb), hi=(int)(((long long)n4*(s+1))/nb);
    const float4* sc4=(const float4*)in.sc[L];
    const float4* on4=(const float4*)in.on[L];
    for (int i=t;i<2048;i+=256) h[i]=0;
    __syncthreads();
    float onsum=0.f;
    for (int i=lo+t;i<hi;i+=256){
      float4 v=sc4[i];
      atomicAdd(&h[(__float_as_uint(v.x)&0x7fffffffu)>>20],1);
      atomicAdd(&h[(__float_as_uint(v.y)&0x7fffffffu)>>20],1);
      atomicAdd(&h[(__float_as_uint(v.z)&0x7fffffffu)>>20],1);
      atomicAdd(&h[(__float_as_uint(v.w)&0x7fffffffu)>>20],1);
      float4 o=on4[i];
      onsum+=(o.x+o.y)+(o.z+o.w);
    }
    __syncthreads();
    unsigned* GH=(unsigned*)(ws+OFF_HIST);
    for (int i=t;i<2048;i+=256) GH[bw*2048+i]=(unsigned)h[i];
    float S=blk_sum(onsum,red,t);
    if (t==0) ws[OFF_ONS+bw]=S;
  }
}

// ---------------- KW2: (block0: reduce pooled min/max, init GMM) + exact radix-select + weight writes
__global__ __launch_bounds__(1024) void kw2_kernel(InPtrs in, float* __restrict__ ws){
  const int t=threadIdx.x;
  const int L=blockIdx.x;
  __shared__ int hist[2048];
  __shared__ int suf[1024];
  __shared__ int sh2[2];
  __shared__ float redm[1024];
  __shared__ float redx[1024];

  if (L==0){
    float mn=3.4e38f,mx=-3.4e38f;
    if (t<NBA){ mn=ws[OFF_MMA+2*t]; mx=ws[OFF_MMA+2*t+1]; }
    redm[t]=mn; redx[t]=mx; __syncthreads();
    for (int s=512;s>0;s>>=1){
      if (t<s){ redm[t]=fminf(redm[t],redm[t+s]); redx[t]=fmaxf(redx[t],redx[t+s]); }
      __syncthreads();
    }
    unsigned* U=(unsigned*)(ws+OFF_GMM);
    if (t==0){ U[0]=fenc(redm[0]); U[1]=fenc(redx[0]); }
    if (t>=2 && t<8) U[t]=(t&1)? 0u : 0xFFFFFFFFu;
    __syncthreads();
  }

  const int N=KW_N[L];
  const int n4=N>>2;
  const int K=N>>1;
  const float4* sc4=(const float4*)in.sc[L];
  const unsigned* GH=(const unsigned*)(ws+OFF_HIST);
  // pass 1: merge slice histograms (bits [30:20])
  for (int i=t;i<2048;i+=1024){
    int s=0;
    for (int bw=KW_BW0[L]; bw<KW_BW1[L]; ++bw) s+=(int)GH[bw*2048+i];
    hist[i]=s;
  }
  __syncthreads();
  int2 f1=find_hist(hist,2048,K,t,suf,sh2);
  const unsigned b0=(unsigned)f1.x; const int r1=f1.y;

  // pass 2: bits [19:10]
  hist[t]=0;
  __syncthreads();
  for (int i=t;i<n4;i+=1024){
    float4 v=sc4[i];
    unsigned ux=__float_as_uint(v.x)&0x7fffffffu;
    unsigned uy=__float_as_uint(v.y)&0x7fffffffu;
    unsigned uz=__float_as_uint(v.z)&0x7fffffffu;
    unsigned uw=__float_as_uint(v.w)&0x7fffffffu;
    if ((ux>>20)==b0) atomicAdd(&hist[(ux>>10)&1023u],1);
    if ((uy>>20)==b0) atomicAdd(&hist[(uy>>10)&1023u],1);
    if ((uz>>20)==b0) atomicAdd(&hist[(uz>>10)&1023u],1);
    if ((uw>>20)==b0) atomicAdd(&hist[(uw>>10)&1023u],1);
  }
  __syncthreads();
  int2 f2=find_hist(hist,1024,r1,t,suf,sh2);
  const unsigned b1=(unsigned)f2.x; const int r2=f2.y;
  const unsigned pre=(b0<<10)|b1;

  // pass 3: bits [9:0]
  hist[t]=0;
  __syncthreads();
  for (int i=t;i<n4;i+=1024){
    float4 v=sc4[i];
    unsigned ux=__float_as_uint(v.x)&0x7fffffffu;
    unsigned uy=__float_as_uint(v.y)&0x7fffffffu;
    unsigned uz=__float_as_uint(v.z)&0x7fffffffu;
    unsigned uw=__float_as_uint(v.w)&0x7fffffffu;
    if ((ux>>10)==pre) atomicAdd(&hist[ux&1023u],1);
    if ((uy>>10)==pre) atomicAdd(&hist[uy&1023u],1);
    if ((uz>>10)==pre) atomicAdd(&hist[uz&1023u],1);
    if ((uw>>10)==pre) atomicAdd(&hist[uw&1023u],1);
  }
  __syncthreads();
  int2 f3=find_hist(hist,1024,r2,t,suf,sh2);
  const unsigned T=(pre<<10)|(unsigned)f3.x;
  if (t==0){
    ((unsigned*)(ws+OFF_T))[L]=T;
    float os=0.f;
    for (int bw=KW_BW0[L]; bw<KW_BW1[L]; ++bw) os+=ws[OFF_ONS+bw];
    ws[OFF_WSC+L]=(os/(float)N)*sqrtf((float)KW_FAN[L])*0.5f;
  }
  __syncthreads();

  // ---- weight writes: lane-linear fragment-major layouts ----
  unsigned short* W1F=(unsigned short*)(ws+OFF_W1M);   // [ocT][h][quad][oc16][8]
  if (L==0){
    unsigned* z=(unsigned*)W1F;           // zero all 4096 u16 (2048 dwords): k>=9 pads
    if (t<1024){ z[t]=0u; z[t+1024]=0u; }
    __syncthreads();
  }
  const float4* sg4=(const float4*)in.sg[L];
  const float4* on4=(const float4*)in.on[L];
  const float4* ze4=(const float4*)in.ze[L];
  float* wout=ws+(L==2?OFF_W3:OFF_W4);
  unsigned short* W2F=(unsigned short*)(ws+OFF_W2);    // [kykx][s][h][quad][oc16][8]
  for (int i4=t;i4<n4;i4+=1024){
    float4 sv4=sc4[i4], g=sg4[i4], o=on4[i4], z=ze4[i4];
    float sv[4]={sv4.x,sv4.y,sv4.z,sv4.w}, gv[4]={g.x,g.y,g.z,g.w};
    float ov[4]={o.x,o.y,o.z,o.w}, zv[4]={z.x,z.y,z.z,z.w};
    #pragma unroll
    for (int j=0;j<4;++j){
      int i=i4*4+j;
      unsigned u=__float_as_uint(sv[j])&0x7fffffffu;
      float w=gv[j]*((u>=T)? ov[j] : zv[j]);
      if (L==0){
        int oc=i/9; int k=i-oc*9;
        int ocT=oc>>4, ocL=oc&15, quad=k>>3, kj=k&7;
        unsigned short hb=f2bf(w);
        float lo2=w-__uint_as_float((unsigned)hb<<16);
        W1F[((((ocT*2+0)*4+quad)*16+ocL)<<3)+kj]=hb;
        W1F[((((ocT*2+1)*4+quad)*16+ocL)<<3)+kj]=f2bf(lo2);
      } else if (L==1){
        int oc=i/576; int r=i-oc*576; int ic=r/9; int kp=r-ic*9;
        int s=ic>>5, rem=ic&31, quad=rem>>3, kj=rem&7;
        unsigned short hb=f2bf(w);
        float lo2=w-__uint_as_float((unsigned)hb<<16);
        W2F[(((((kp*2+s)*2+0)*4+quad)*16+oc)<<3)+kj]=hb;
        W2F[(((((kp*2+s)*2+1)*4+quad)*16+oc)<<3)+kj]=f2bf(lo2);
      } else {
        int o2;
        if (L==2){ int oc=i/400; int kk=i-oc*400; o2=kk*128+oc; }
        else o2=i;
        wout[o2]=w;
      }
    }
  }
}

// ---------------- KB: conv1 via MFMA -> per-channel BN1 stats partials (1 img/block) ----------------
__global__ __launch_bounds__(256) void kb_kernel(InPtrs in, const float* __restrict__ wsr, float* __restrict__ wsw){
  const int t=threadIdx.x, blk=blockIdx.x;
  __shared__ unsigned short qxs[256];
  __shared__ __align__(16) unsigned PAT[2880];   // patches [pos144][20 dwords = 40 u16, k0..31 used]
  __shared__ float xw[1024];
  const float* pooled=wsr+OFF_POOLED;
  const unsigned* U=(const unsigned*)(wsr+OFF_GMM);
  const float mn0=fdec(U[0]);
  const float mx0=fdec(U[1]);
  const float lvf=(float)((1<<in.qb[0])-1);
  const float s0=(mx0-mn0)/lvf, inv_s0=1.0f/s0, zp0=floorf(mn0/s0);
  const float sv=s0/wsr[OFF_WSC+0];
  if (t<224){
    int row=t>>4, col=t&15;
    float q=0.f;
    if (col<14){ float xx=pooled[(size_t)blk*196+row*14+col]; q=rintf((xx-mn0)*inv_s0)+zp0; }
    qxs[t]=(unsigned short)(__float_as_uint(q)>>16);
  }
  __syncthreads();
  for (int idx=t; idx<2304; idx+=256){
    int pos=idx>>4, kd=idx&15;
    int py=pos/12, px=pos-py*12;
    unsigned c0=0u,c1=0u;
    int k0=kd*2;
    if (k0<9){ int ky=k0/3,kx=k0-ky*3; c0=qxs[(py+ky)*16+px+kx]; }
    if (k0+1<9){ int k1=k0+1; int ky=k1/3,kx=k1-ky*3; c1=qxs[(py+ky)*16+px+kx]; }
    PAT[pos*20+kd]=c0|(c1<<16);
  }
  __syncthreads();
  {
    const int w=t>>6, lane=t&63;
    const int l15=lane&15, quad=lane>>4;
    const unsigned short* W1F=(const unsigned short*)(wsr+OFF_W1M);
    const unsigned short* PATu=(const unsigned short*)PAT;
    #pragma unroll
    for (int ocT=0; ocT<4; ++ocT){
      bf16x8 bh=*(const bf16x8*)(W1F+(((ocT*2+0)*64+lane)<<3));   // lane-linear 1KB span
      bf16x8 bl=*(const bf16x8*)(W1F+(((ocT*2+1)*64+lane)<<3));
      float sum=0.f,sq=0.f,mn=3.4e38f,mx=-3.4e38f;
      for (int tl=w; tl<9; tl+=4){
        bf16x8 a=*(const bf16x8*)(PATu+(tl*16+l15)*40+quad*8);
        f32x4 acc=(f32x4){0.f,0.f,0.f,0.f};
        acc=__builtin_amdgcn_mfma_f32_16x16x32_bf16(a,bh,acc,0,0,0);
        acc=__builtin_amdgcn_mfma_f32_16x16x32_bf16(a,bl,acc,0,0,0);
        #pragma unroll
        for (int r=0;r<4;++r){
          float v=acc[r]*sv;
          sum+=v; sq=fmaf(v,v,sq); mn=fminf(mn,v); mx=fmaxf(mx,v);
        }
      }
      #pragma unroll
      for (int d=16;d<64;d<<=1){
        sum+=__shfl_xor(sum,d);
        sq +=__shfl_xor(sq,d);
        mn=fminf(mn,__shfl_xor(mn,d));
        mx=fmaxf(mx,__shfl_xor(mx,d));
      }
      if (quad==0){
        float* p=xw+((w*4+ocT)*16+l15)*4;
        p[0]=sum; p[1]=sq; p[2]=mn; p[3]=mx;
      }
    }
  }
  __syncthreads();
  if (t<64){
    float sum=0.f,sq=0.f,mn=3.4e38f,mx=-3.4e38f;
    #pragma unroll
    for (int w=0;w<4;++w){
      const float* p=xw+((w*4+(t>>4))*16+(t&15))*4;
      sum+=p[0]; sq+=p[1]; mn=fminf(mn,p[2]); mx=fmaxf(mx,p[3]);
    }
    float* p=wsw+OFF_ST1+((size_t)t*NBB+blk)*4;
    p[0]=sum; p[1]=sq; p[2]=mn; p[3]=mx;
  }
}

// ---------------- kstat ----------------
__global__ __launch_bounds__(256) void kstat_kernel(const float* __restrict__ wsr, float* __restrict__ wsw,
                                                    unsigned long long inoff, int nparts, float Nf,
                                                    unsigned long long outoff, int mmslot){
  const int c=blockIdx.x, t=threadIdx.x;
  __shared__ float red[256];
  const float* p=wsr+inoff+(size_t)c*nparts*4;
  float sum=0.f,sq=0.f,mn=3.4e38f,mx=-3.4e38f;
  for (int i=t;i<nparts;i+=256){
    sum+=p[i*4]; sq+=p[i*4+1];
    mn=fminf(mn,p[i*4+2]); mx=fmaxf(mx,p[i*4+3]);
  }
  float S=blk_sum(sum,red,t);
  float Q=blk_sum(sq,red,t);
  float MN=blk_min(mn,red,t);
  float MX=blk_max(mx,red,t);
  if (t==0){
    float mean=S/Nf;
    float var=fmaxf(Q/Nf-mean*mean,0.f);
    float sd=sqrtf(var+1e-5f);
    float* o=wsw+outoff+c*4;
    float tmn=(MN-mean)/sd, tmx=(MX-mean)/sd;
    o[0]=mean; o[1]=sd; o[2]=tmn; o[3]=tmx;
    unsigned* U=(unsigned*)(wsw+OFF_GMM);
    atomicMin(&U[mmslot],fenc(tmn));
    atomicMax(&U[mmslot+1],fenc(tmx));
  }
}

// ---------------- KC: conv1(MFMA)->bn1/relu/quant->conv2(MFMA)->pool, 1 img/block ----------------
__global__ __launch_bounds__(256) void kc_kernel(InPtrs in, const float* __restrict__ wsr, float* __restrict__ wsw){
  const int t=threadIdx.x, blk=blockIdx.x;
  __shared__ unsigned short qxs[256];
  __shared__ __align__(16) unsigned PAT[2880];           // patches; aliased by c2s after conv1
  __shared__ __align__(16) unsigned short actA[144*72];  // [cell][72: 64 ch + 8 pad] bf16 codes
  __shared__ float sA2[64], sB2[64];
  __shared__ float stsum[16], stsq[16];
  __shared__ unsigned stmn[16], stmx[16];
  float* c2s=(float*)PAT;                                // [oc16][100] conv2 out
  const float* pooled=wsr+OFF_POOLED;
  const unsigned* U=(const unsigned*)(wsr+OFF_GMM);
  const float mn0=fdec(U[0]);
  const float mx0=fdec(U[1]);
  const float rmn=fdec(U[2]);
  const float rmx=fdec(U[3]);
  const float lvf=(float)((1<<in.qb[0])-1);
  const float s0=(mx0-mn0)/lvf, inv_s0=1.0f/s0, zp0=floorf(mn0/s0);
  const float s1w=wsr[OFF_WSC+0], s2w=wsr[OFF_WSC+1];
  const float s2=(fmaxf(rmx,0.f)-fmaxf(rmn,0.f))/lvf;
  const float inv_s2=1.0f/s2;
  const float g2=s2/s2w;
  if (t<64){
    float m=wsr[OFF_BN1+t*4], sd=wsr[OFF_BN1+t*4+1];
    sA2[t]=s0/(s1w*sd);
    sB2[t]=-m/sd;
  }
  if (t<16){ stsum[t]=0.f; stsq[t]=0.f; stmn[t]=0xFFFFFFFFu; stmx[t]=0u; }
  if (t<224){
    int row=t>>4, col=t&15;
    float q=0.f;
    if (col<14){ float xx=pooled[(size_t)blk*196+row*14+col]; q=rintf((xx-mn0)*inv_s0)+zp0; }
    qxs[t]=(unsigned short)(__float_as_uint(q)>>16);
  }
  __syncthreads();
  for (int idx=t; idx<2304; idx+=256){
    int pos=idx>>4, kd=idx&15;
    int py=pos/12, px=pos-py*12;
    unsigned c0=0u,c1=0u;
    int k0=kd*2;
    if (k0<9){ int ky=k0/3,kx=k0-ky*3; c0=qxs[(py+ky)*16+px+kx]; }
    if (k0+1<9){ int k1=k0+1; int ky=k1/3,kx=k1-ky*3; c1=qxs[(py+ky)*16+px+kx]; }
    PAT[pos*20+kd]=c0|(c1<<16);
  }
  __syncthreads();
  // conv1 MFMA + bn/relu/quant -> actA
  {
    const int w=t>>6, lane=t&63;
    const int l15=lane&15, quad=lane>>4;
    const unsigned short* W1F=(const unsigned short*)(wsr+OFF_W1M);
    const unsigned short* PATu=(const unsigned short*)PAT;
    #pragma unroll
    for (int ocT=0; ocT<4; ++ocT){
      bf16x8 bh=*(const bf16x8*)(W1F+(((ocT*2+0)*64+lane)<<3));
      bf16x8 bl=*(const bf16x8*)(W1F+(((ocT*2+1)*64+lane)<<3));
      const int oc=ocT*16+l15;
      const float a2=sA2[oc], b2=sB2[oc];
      for (int tl=w; tl<9; tl+=4){
        bf16x8 a=*(const bf16x8*)(PATu+(tl*16+l15)*40+quad*8);
        f32x4 acc=(f32x4){0.f,0.f,0.f,0.f};
        acc=__builtin_amdgcn_mfma_f32_16x16x32_bf16(a,bh,acc,0,0,0);
        acc=__builtin_amdgcn_mfma_f32_16x16x32_bf16(a,bl,acc,0,0,0);
        #pragma unroll
        for (int r=0;r<4;++r){
          int pos=tl*16+quad*4+r;
          float f=fminf(rintf(fmaxf(fmaf(acc[r],a2,b2),0.f)*inv_s2),lvf);
          actA[pos*72+oc]=(unsigned short)(__float_as_uint(f)>>16);
        }
      }
    }
  }
  __syncthreads();
  // conv2 via MFMA: 7 M-tiles of 16 positions; wave w gets tau=w, w+4
  {
    const int w=t>>6, lane=t&63;
    const int oc=lane&15, quad=lane>>4;
    const unsigned short* W2F=(const unsigned short*)(wsr+OFF_W2);
    const int nT=(w<3)?2:1;
    int abase[2]; int taus[2];
    for (int i=0;i<nT;++i){
      int tau=w+i*4;
      int posb=tau*16+(lane&15);
      int pc=posb>99?99:posb;
      int py=pc/10, px=pc-py*10;
      abase[i]=(py*12+px)*72+quad*8;
      taus[i]=tau;
    }
    f32x4 acc[2];
    acc[0]=(f32x4){0.f,0.f,0.f,0.f};
    acc[1]=(f32x4){0.f,0.f,0.f,0.f};
    #pragma unroll 1
    for (int kykx=0;kykx<9;++kykx){
      const int co=((kykx/3)*12+(kykx%3))*72;
      #pragma unroll
      for (int s=0;s<2;++s){
        bf16x8 bh=*(const bf16x8*)(W2F+((((kykx*2+s)*2+0)*64+lane)<<3));  // lane-linear 1KB
        bf16x8 bl=*(const bf16x8*)(W2F+((((kykx*2+s)*2+1)*64+lane)<<3));
        #pragma unroll
        for (int i=0;i<2;++i){
          if (i<nT){
            bf16x8 a=*(const bf16x8*)(actA+abase[i]+co+s*32);
            acc[i]=__builtin_amdgcn_mfma_f32_16x16x32_bf16(a,bh,acc[i],0,0,0);
            acc[i]=__builtin_amdgcn_mfma_f32_16x16x32_bf16(a,bl,acc[i],0,0,0);
          }
        }
      }
    }
    __syncthreads();   // PAT + actA reads done -> safe to write c2s (aliases PAT)
    for (int i=0;i<nT;++i){
      int pos4=taus[i]*16+quad*4;
      if (pos4<100){
        float4* dst=(float4*)&c2s[oc*100+pos4];
        *dst=make_float4(acc[i].x*g2,acc[i].y*g2,acc[i].z*g2,acc[i].w*g2);
      }
    }
  }
  __syncthreads();
  for (int i=t;i<400;i+=256){
    int ch=i/25, pp=i-ch*25;
    int py=pp/5, px=pp-py*5;
    const float* cc=c2s+ch*100;
    int base=py*20+px*2;
    float v=fmaxf(fmaxf(cc[base],cc[base+1]),fmaxf(cc[base+10],cc[base+11]));
    wsw[OFF_Y2P+(size_t)blk*400+i]=v;
    atomicAdd(&stsum[ch],v);
    atomicAdd(&stsq[ch],v*v);
    atomicMin(&stmn[ch],fenc(v));
    atomicMax(&stmx[ch],fenc(v));
  }
  __syncthreads();
  if (t<16){
    float* p=wsw+OFF_ST2+((size_t)t*NBC+blk)*4;
    p[0]=stsum[t]; p[1]=stsq[t]; p[2]=fdec(stmn[t]); p[3]=fdec(stmx[t]);
  }
}

// ---------------- KE: bn2/relu/quant -> fc1 -> relu, 8 img/block (2 img/wave) ----------------
__global__ __launch_bounds__(256) void ke_kernel(InPtrs in, const float* __restrict__ wsr, float* __restrict__ wsw){
  const int t=threadIdx.x, blk=blockIdx.x;
  __shared__ __align__(16) float xs[3200];
  __shared__ float sm[16], sisd[16];
  const unsigned* U=(const unsigned*)(wsr+OFF_GMM);
  const float lvf=(float)((1<<in.qb[0])-1);
  const float rmn=fdec(U[4]);
  const float rmx=fdec(U[5]);
  if (t<16){ sm[t]=wsr[OFF_BN2+t*4]; sisd[t]=1.0f/wsr[OFF_BN2+t*4+1]; }
  const float s3=(fmaxf(rmx,0.f)-fmaxf(rmn,0.f))/lvf;
  const float inv_s3=1.0f/s3;
  const float inv_s3w=1.0f/wsr[OFF_WSC+2];
  const int b0=blk*8;
  __syncthreads();
  for (int i=t;i<3200;i+=256){
    int img=i/400, k=i-img*400;
    int ch=k/25;
    float y=wsr[OFF_Y2P+(size_t)(b0+img)*400+k];
    float bn=(y-sm[ch])*sisd[ch];
    float r=fmaxf(bn,0.f);
    xs[i]=fminf(rintf(r*inv_s3),lvf)*s3;
  }
  __syncthreads();
  const int w=t>>6, lane=t&63;
  const float* xA=xs+(w*2)*400;
  const float* xB=xs+(w*2+1)*400;
  const float* w3=wsr+OFF_W3;
  float aA0=0.f,aA1=0.f,aB0=0.f,aB1=0.f;
  #pragma unroll 2
  for (int k=0;k<400;k+=4){
    float4 va=*(const float4*)(xA+k);
    float4 vb=*(const float4*)(xB+k);
    float2 w0=*(const float2*)(w3+(k+0)*128+lane*2);
    float2 w1=*(const float2*)(w3+(k+1)*128+lane*2);
    float2 w2=*(const float2*)(w3+(k+2)*128+lane*2);
    float2 wv3=*(const float2*)(w3+(k+3)*128+lane*2);
    aA0=fmaf(va.x,w0.x,aA0); aA1=fmaf(va.x,w0.y,aA1);
    aB0=fmaf(vb.x,w0.x,aB0); aB1=fmaf(vb.x,w0.y,aB1);
    aA0=fmaf(va.y,w1.x,aA0); aA1=fmaf(va.y,w1.y,aA1);
    aB0=fmaf(vb.y,w1.x,aB0); aB1=fmaf(vb.y,w1.y,aB1);
    aA0=fmaf(va.z,w2.x,aA0); aA1=fmaf(va.z,w2.y,aA1);
    aB0=fmaf(vb.z,w2.x,aB0); aB1=fmaf(vb.z,w2.y,aB1);
    aA0=fmaf(va.w,wv3.x,aA0); aA1=fmaf(va.w,wv3.y,aA1);
    aB0=fmaf(vb.w,wv3.x,aB0); aB1=fmaf(vb.w,wv3.y,aB1);
  }
  float hA0=fmaxf(aA0*inv_s3w,0.f), hA1=fmaxf(aA1*inv_s3w,0.f);
  float hB0=fmaxf(aB0*inv_s3w,0.f), hB1=fmaxf(aB1*inv_s3w,0.f);
  *(float2*)(wsw+OFF_H3+(size_t)(b0+w*2)*128+lane*2)=make_float2(hA0,hA1);
  *(float2*)(wsw+OFF_H3+(size_t)(b0+w*2+1)*128+lane*2)=make_float2(hB0,hB1);
  float hmn=fminf(fminf(hA0,hA1),fminf(hB0,hB1));
  float hmx=fmaxf(fmaxf(hA0,hA1),fmaxf(hB0,hB1));
  #pragma unroll
  for (int d=1;d<64;d<<=1){
    hmn=fminf(hmn,__shfl_xor(hmn,d));
    hmx=fmaxf(hmx,__shfl_xor(hmx,d));
  }
  if (lane==0){
    unsigned* Uw=(unsigned*)(wsw+OFF_GMM);
    atomicMin(&Uw[6],fenc(hmn));
    atomicMax(&Uw[7],fenc(hmx));
  }
}

// ---------------- KF: quant -> fc2 -> log_softmax; 64 rows/block, 4 lanes/row ----------------
__global__ __launch_bounds__(256) void kf_kernel(InPtrs in, const float* __restrict__ wsr, float* __restrict__ out){
  const int t=threadIdx.x, blk=blockIdx.x;
  __shared__ float w4s[1280];
  const unsigned* U=(const unsigned*)(wsr+OFF_GMM);
  const float lvf=(float)((1<<in.qb[0])-1);
  const float hmn=fdec(U[6]);
  const float hmx=fdec(U[7]);
  for (int i=t;i<1280;i+=256) w4s[i]=wsr[OFF_W4+i];
  const float s4=(hmx-hmn)/lvf;
  const float inv_s4=1.0f/s4;
  const float inv_s4w=1.0f/wsr[OFF_WSC+3];
  __syncthreads();
  const int row=blk*64+(t>>2), l4=t&3;
  const float4* hr4=(const float4*)(wsr+OFF_H3+(size_t)row*128);
  float acc[10];
  #pragma unroll
  for (int j=0;j<10;++j) acc[j]=0.f;
  #pragma unroll 2
  for (int j=0;j<8;++j){
    float4 v=hr4[l4*8+j];
    int kb=(l4*8+j)*4;
    float q0=fminf(rintf(v.x*inv_s4),lvf)*s4;
    float q1=fminf(rintf(v.y*inv_s4),lvf)*s4;
    float q2=fminf(rintf(v.z*inv_s4),lvf)*s4;
    float q3=fminf(rintf(v.w*inv_s4),lvf)*s4;
    #pragma unroll
    for (int o=0;o<10;++o){
      const float* wr=w4s+o*128+kb;
      acc[o]=fmaf(q0,wr[0],acc[o]);
      acc[o]=fmaf(q1,wr[1],acc[o]);
      acc[o]=fmaf(q2,wr[2],acc[o]);
      acc[o]=fmaf(q3,wr[3],acc[o]);
    }
  }
  #pragma unroll
  for (int o=0;o<10;++o){
    acc[o]+=__shfl_xor(acc[o],1);
    acc[o]+=__shfl_xor(acc[o],2);
  }
  if (l4==0){
    float mx=-3.4e38f;
    #pragma unroll
    for (int o=0;o<10;++o){ acc[o]*=inv_s4w; mx=fmaxf(mx,acc[o]); }
    float se=0.f;
    #pragma unroll
    for (int o=0;o<10;++o) se+=expf(acc[o]-mx);
    const float ls=logf(se);
    #pragma unroll
    for (int o=0;o<10;++o) out[row*10+o]=acc[o]-mx-ls;
  }
}

extern "C" void kernel_launch(void* const* d_in, const int* in_sizes, int n_in,
                              void* d_out, int out_size, void* d_ws, size_t ws_size,
                              hipStream_t stream){
  (void)in_sizes; (void)n_in; (void)out_size; (void)ws_size;
  InPtrs P;
  P.x=(const float*)d_in[0];
  for (int l=0;l<4;++l){
    P.sc[l]=(const float*)d_in[1+l*4];
    P.sg[l]=(const float*)d_in[2+l*4];
    P.on[l]=(const float*)d_in[3+l*4];
    P.ze[l]=(const float*)d_in[4+l*4];
  }
  P.qb=(const int*)d_in[17];
  float* ws=(float*)d_ws;

  hipLaunchKernelGGL(ka_kernel,  dim3(NBA+NBW), dim3(256),  0, stream, P, ws);
  hipLaunchKernelGGL(kw2_kernel, dim3(4),       dim3(1024), 0, stream, P, ws);
  hipLaunchKernelGGL(kb_kernel,  dim3(NBB),     dim3(256),  0, stream, P, ws, ws);
  hipLaunchKernelGGL(kstat_kernel, dim3(64), dim3(256), 0, stream, ws, ws,
                     (unsigned long long)OFF_ST1, NBB, 4096.f*144.f, (unsigned long long)OFF_BN1, 2);
  hipLaunchKernelGGL(kc_kernel,  dim3(NBC),     dim3(256),  0, stream, P, ws, ws);
  hipLaunchKernelGGL(kstat_kernel, dim3(16), dim3(256), 0, stream, ws, ws,
                     (unsigned long long)OFF_ST2, NBC, 4096.f*25.f, (unsigned long long)OFF_BN2, 4);
  hipLaunchKernelGGL(ke_kernel,  dim3(NBE),     dim3(256),  0, stream, P, ws, ws);
  hipLaunchKernelGGL(kf_kernel,  dim3(64),      dim3(256),  0, stream, P, ws, (float*)d_out);
}

// Round 10
// 333.052 us; speedup vs baseline: 1.2050x; 1.0687x over previous
//
#include <hip/hip_runtime.h>
#include <hip/hip_bf16.h>
#include <math.h>

#define DEV __device__ __forceinline__

constexpr int BATCH = 4096;
constexpr int NBA = 512;    // pool blocks (ka also carries 16 hist blocks)
constexpr int NBB = 4096;   // conv1-stats blocks (1 img each, MFMA)
constexpr int NBC = 4096;   // fused conv blocks (1 img each)
constexpr int NBE = 512;    // fc1 blocks (8 img each)
constexpr int NBW = 16;     // hist slices

// workspace layout (float offsets)
constexpr size_t OFF_POOLED = 0;                            // 4096*196
constexpr size_t OFF_Y2P = OFF_POOLED + (size_t)BATCH*196;  // 4096*400
constexpr size_t OFF_ST1 = OFF_Y2P;                         // 64*4096*4; consumed by kstat1 BEFORE kc writes Y2P
constexpr size_t OFF_H3  = OFF_Y2P + (size_t)BATCH*400;     // 4096*128
constexpr size_t OFF_ST2 = OFF_H3;                          // 16*4096*4; consumed by kstat2 BEFORE ke writes H3
constexpr size_t OFF_W2  = OFF_H3 + (size_t)BATCH*128;      // W2F u16[9][2][2][4][16][8] lane-linear
constexpr size_t OFF_W3  = OFF_W2 + 9216;                   // 51200 [k*128+oc]
constexpr size_t OFF_W4  = OFF_W3 + 51200;                  // 1280 [oc*128+k]
constexpr size_t OFF_WSC = OFF_W4 + 1280;                   // 4 layer scales
constexpr size_t OFF_BN1 = OFF_WSC + 4;                     // 64*4
constexpr size_t OFF_BN2 = OFF_BN1 + 256;                   // 16*4
constexpr size_t OFF_GMM = OFF_BN2 + 64;                    // 8 encoded slots
constexpr size_t OFF_ONS = OFF_GMM + 8;                     // 16 per-slice sum(hw_one)
constexpr size_t OFF_T   = OFF_ONS + 16;                    // (unused)
constexpr size_t OFF_MMA = OFF_T + 4;                       // 512*2 pooled min/max partials
constexpr size_t OFF_HIST= OFF_MMA + 1024;                  // 16*2048 per-slice pass-1 histograms
constexpr size_t OFF_W1M = OFF_HIST + 32768;                // W1F u16[4][2][4][16][8] (2048 floats)
constexpr size_t OFF_SEL = OFF_W1M + 2048;                  // 8 uints: per-L {b0, r1}
constexpr size_t OFF_H2G = OFF_SEL + 8;                     // 4*1024 uints pass-2 global hists
constexpr size_t OFF_H3G = OFF_H2G + 4096;                  // 4*1024 uints pass-3 global hists
// GMM: [0]=pooled min [1]=pooled max [2]=bn1 tmin [3]=bn1 tmax [4]=bn2 tmin [5]=bn2 tmax [6]=fc1 min [7]=fc1 max

typedef __attribute__((ext_vector_type(8))) short bf16x8;
typedef __attribute__((ext_vector_type(4))) float f32x4;

struct InPtrs {
  const float* x;
  const float* sc[4];
  const float* sg[4];
  const float* on[4];
  const float* ze[4];
  const int* qb;
};

// hist-slice partition: 16 slices over 4 layers
__constant__ const int KW_L[16]  ={0,1,1,2,2,2,2,2,2,2,2,2,2,2,2,3};
__constant__ const int KW_S[16]  ={0,0,1,0,1,2,3,4,5,6,7,8,9,10,11,0};
__constant__ const int KW_NB[4]  ={1,2,12,1};
__constant__ const int KW_N[4]   ={576,9216,51200,1280};
__constant__ const int KW_FAN[4] ={9,576,400,128};
__constant__ const int KW_BW0[4] ={0,1,3,15};
__constant__ const int KW_BW1[4] ={1,3,15,16};

DEV unsigned fenc(float f){ unsigned u=__float_as_uint(f); return (u&0x80000000u)? ~u : (u|0x80000000u); }
DEV float fdec(unsigned e){ return __uint_as_float((e&0x80000000u)? (e&0x7fffffffu) : ~e); }
DEV unsigned short f2bf(float f){ unsigned u=__float_as_uint(f); return (unsigned short)((u + 0x7fffu + ((u>>16)&1u))>>16); }

DEV float blk_sum(float v, float* red, int t){
  red[t]=v; __syncthreads();
  for (int s=128;s>0;s>>=1){ if(t<s) red[t]+=red[t+s]; __syncthreads(); }
  float r=red[0]; __syncthreads();
  return r;
}
DEV float blk_min(float v, float* red, int t){
  red[t]=v; __syncthreads();
  for (int s=128;s>0;s>>=1){ if(t<s) red[t]=fminf(red[t],red[t+s]); __syncthreads(); }
  float r=red[0]; __syncthreads();
  return r;
}
DEV float blk_max(float v, float* red, int t){
  red[t]=v; __syncthreads();
  for (int s=128;s>0;s>>=1){ if(t<s) red[t]=fmaxf(red[t],red[t+s]); __syncthreads(); }
  float r=red[0]; __syncthreads();
  return r;
}

// find bucket from top with 256 threads; nbins in {1024,2048}; returns {bucket, remainder}
DEV int2 find256(const int* hist, int nbins, int kk, int t, int* suf, int* sh2){
  const int G=nbins>>8;
  const int lo=t*G;
  int g=0;
  for (int b=0;b<G;++b) g+=hist[lo+b];
  suf[t]=g; __syncthreads();
  for (int s=1;s<256;s<<=1){
    int add=(t+s<256)?suf[t+s]:0;
    __syncthreads();
    suf[t]+=add;
    __syncthreads();
  }
  const int S=suf[t];
  const int Snext=(t<255)?suf[t+1]:0;
  if (S>=kk && Snext<kk){
    int c2=Snext;
    for (int b=lo+G-1;b>=lo;--b){
      c2+=hist[b];
      if (c2>=kk){ sh2[0]=b; sh2[1]=kk-(c2-hist[b]); break; }
    }
  }
  __syncthreads();
  int2 r=make_int2(sh2[0],sh2[1]);
  __syncthreads();
  return r;
}

// ---------------- KA: blocks<512: maxpool + min/max partials (block0 also zeroes pass2/3 hists).
//                    blocks 512..527: per-slice pass-1 histogram + sum(hw_one).
__global__ __launch_bounds__(256) void ka_kernel(InPtrs in, float* __restrict__ ws){
  const int t=threadIdx.x, blk=blockIdx.x;
  __shared__ int h[2048];
  __shared__ float red[256];
  if (blk<NBA){
    if (blk==0){
      unsigned* Z=(unsigned*)(ws+OFF_H2G);
      for (int i=t;i<8192;i+=256) Z[i]=0u;
    }
    const float* x=in.x;
    float* pooled=ws+OFF_POOLED;
    float lmn=3.4e38f, lmx=-3.4e38f;
    for (int p=blk*256+t; p<BATCH*196; p+=NBA*256){
      int b=p/196, r=p-b*196;
      int oy=r/14, ox=r-oy*14;
      const float* px=x+b*784+oy*56+ox*2;
      float m=fmaxf(fmaxf(px[0],px[1]),fmaxf(px[28],px[29]));
      pooled[p]=m;
      lmn=fminf(lmn,m); lmx=fmaxf(lmx,m);
    }
    float bmn=blk_min(lmn,red,t);
    float bmx=blk_max(lmx,red,t);
    if (t==0){ ws[OFF_MMA+blk*2]=bmn; ws[OFF_MMA+blk*2+1]=bmx; }
  } else {
    const int bw=blk-NBA;
    const int L=KW_L[bw], s=KW_S[bw], nb=KW_NB[L];
    const int n4=KW_N[L]>>2;
    const int lo=(int)(((long long)n4*s)/nb), hi=(int)(((long long)n4*(s+1))/nb);
    const float4* sc4=(const float4*)in.sc[L];
    const float4* on4=(const float4*)in.on[L];
    for (int i=t;i<2048;i+=256) h[i]=0;
    __syncthreads();
    float onsum=0.f;
    for (int i=lo+t;i<hi;i+=256){
      float4 v=sc4[i];
      atomicAdd(&h[(__float_as_uint(v.x)&0x7fffffffu)>>20],1);
      atomicAdd(&h[(__float_as_uint(v.y)&0x7fffffffu)>>20],1);
      atomicAdd(&h[(__float_as_uint(v.z)&0x7fffffffu)>>20],1);
      atomicAdd(&h[(__float_as_uint(v.w)&0x7fffffffu)>>20],1);
      float4 o=on4[i];
      onsum+=(o.x+o.y)+(o.z+o.w);
    }
    __syncthreads();
    unsigned* GH=(unsigned*)(ws+OFF_HIST);
    for (int i=t;i<2048;i+=256) GH[bw*2048+i]=(unsigned)h[i];
    float S=blk_sum(onsum,red,t);
    if (t==0) ws[OFF_ONS+bw]=S;
  }
}

// ---------------- KW2A: per-L merge pass-1 hists + find (b0,r1); block0: pooled reduce + GMM init + W1F zero
__global__ __launch_bounds__(256) void kw2a_kernel(float* __restrict__ ws){
  const int t=threadIdx.x, L=blockIdx.x;
  __shared__ int hist[2048];
  __shared__ int suf[256];
  __shared__ int sh2[2];
  __shared__ float redm[256], redx[256];
  if (L==0){
    float a0=ws[OFF_MMA+2*t],       a1=ws[OFF_MMA+2*(t+256)];
    float b0=ws[OFF_MMA+2*t+1],     b1=ws[OFF_MMA+2*(t+256)+1];
    redm[t]=fminf(a0,a1); redx[t]=fmaxf(b0,b1);
    __syncthreads();
    for (int s=128;s>0;s>>=1){
      if (t<s){ redm[t]=fminf(redm[t],redm[t+s]); redx[t]=fmaxf(redx[t],redx[t+s]); }
      __syncthreads();
    }
    unsigned* U=(unsigned*)(ws+OFF_GMM);
    if (t==0){ U[0]=fenc(redm[0]); U[1]=fenc(redx[0]); }
    if (t>=2 && t<8) U[t]=(t&1)? 0u : 0xFFFFFFFFu;
    unsigned* z=(unsigned*)(ws+OFF_W1M);     // zero W1F (k>=9 pads)
    for (int i=t;i<2048;i+=256) z[i]=0u;
    __syncthreads();
  }
  const unsigned* GH=(const unsigned*)(ws+OFF_HIST);
  for (int i=t;i<2048;i+=256){
    int s=0;
    for (int bw=KW_BW0[L]; bw<KW_BW1[L]; ++bw) s+=(int)GH[bw*2048+i];
    hist[i]=s;
  }
  __syncthreads();
  int2 f1=find256(hist,2048,KW_N[L]>>1,t,suf,sh2);
  if (t==0){
    unsigned* SEL=(unsigned*)(ws+OFF_SEL);
    SEL[L*2]=(unsigned)f1.x; SEL[L*2+1]=(unsigned)f1.y;
  }
}

// ---------------- KWP2: slice-parallel pass-2 conditional histogram (bits [19:10]) ----------------
__global__ __launch_bounds__(256) void kwp2_kernel(InPtrs in, float* __restrict__ ws){
  const int t=threadIdx.x, bw=blockIdx.x;
  const int L=KW_L[bw], s=KW_S[bw], nb=KW_NB[L];
  const int n4=KW_N[L]>>2;
  const int lo=(int)(((long long)n4*s)/nb), hi=(int)(((long long)n4*(s+1))/nb);
  const unsigned b0=((const unsigned*)(ws+OFF_SEL))[L*2];
  const float4* sc4=(const float4*)in.sc[L];
  unsigned* GH2=(unsigned*)(ws+OFF_H2G)+L*1024;
  for (int i=lo+t;i<hi;i+=256){
    float4 v=sc4[i];
    unsigned ux=__float_as_uint(v.x)&0x7fffffffu;
    unsigned uy=__float_as_uint(v.y)&0x7fffffffu;
    unsigned uz=__float_as_uint(v.z)&0x7fffffffu;
    unsigned uw=__float_as_uint(v.w)&0x7fffffffu;
    if ((ux>>20)==b0) atomicAdd(&GH2[(ux>>10)&1023u],1u);
    if ((uy>>20)==b0) atomicAdd(&GH2[(uy>>10)&1023u],1u);
    if ((uz>>20)==b0) atomicAdd(&GH2[(uz>>10)&1023u],1u);
    if ((uw>>20)==b0) atomicAdd(&GH2[(uw>>10)&1023u],1u);
  }
}

// ---------------- KWP3: per-block find (b1,r2) over hist2, then pass-3 conditional histogram ----------------
__global__ __launch_bounds__(256) void kwp3_kernel(InPtrs in, float* __restrict__ ws){
  const int t=threadIdx.x, bw=blockIdx.x;
  const int L=KW_L[bw], s=KW_S[bw], nb=KW_NB[L];
  const int n4=KW_N[L]>>2;
  const int lo=(int)(((long long)n4*s)/nb), hi=(int)(((long long)n4*(s+1))/nb);
  const unsigned* SEL=(const unsigned*)(ws+OFF_SEL);
  const unsigned b0=SEL[L*2]; const int r1=(int)SEL[L*2+1];
  __shared__ int hist[1024];
  __shared__ int suf[256];
  __shared__ int sh2[2];
  const unsigned* GH2=(const unsigned*)(ws+OFF_H2G)+L*1024;
  for (int i=t;i<1024;i+=256) hist[i]=(int)GH2[i];
  __syncthreads();
  int2 f2=find256(hist,1024,r1,t,suf,sh2);
  const unsigned pre=(b0<<10)|(unsigned)f2.x;
  const float4* sc4=(const float4*)in.sc[L];
  unsigned* GH3=(unsigned*)(ws+OFF_H3G)+L*1024;
  for (int i=lo+t;i<hi;i+=256){
    float4 v=sc4[i];
    unsigned ux=__float_as_uint(v.x)&0x7fffffffu;
    unsigned uy=__float_as_uint(v.y)&0x7fffffffu;
    unsigned uz=__float_as_uint(v.z)&0x7fffffffu;
    unsigned uw=__float_as_uint(v.w)&0x7fffffffu;
    if ((ux>>10)==pre) atomicAdd(&GH3[ux&1023u],1u);
    if ((uy>>10)==pre) atomicAdd(&GH3[uy&1023u],1u);
    if ((uz>>10)==pre) atomicAdd(&GH3[uz&1023u],1u);
    if ((uw>>10)==pre) atomicAdd(&GH3[uw&1023u],1u);
  }
}

// ---------------- KW3: per-block finds -> exact T; slice-parallel weight writes ----------------
__global__ __launch_bounds__(256) void kw3_kernel(InPtrs in, float* __restrict__ ws){
  const int t=threadIdx.x, bw=blockIdx.x;
  const int L=KW_L[bw], s=KW_S[bw], nb=KW_NB[L];
  const int n4=KW_N[L]>>2;
  const int lo=(int)(((long long)n4*s)/nb), hi=(int)(((long long)n4*(s+1))/nb);
  const unsigned* SEL=(const unsigned*)(ws+OFF_SEL);
  const unsigned b0=SEL[L*2]; const int r1=(int)SEL[L*2+1];
  __shared__ int hist[1024];
  __shared__ int suf[256];
  __shared__ int sh2[2];
  const unsigned* GH2=(const unsigned*)(ws+OFF_H2G)+L*1024;
  for (int i=t;i<1024;i+=256) hist[i]=(int)GH2[i];
  __syncthreads();
  int2 f2=find256(hist,1024,r1,t,suf,sh2);
  const unsigned pre=(b0<<10)|(unsigned)f2.x;
  const int r2=f2.y;
  __syncthreads();
  const unsigned* GH3=(const unsigned*)(ws+OFF_H3G)+L*1024;
  for (int i=t;i<1024;i+=256) hist[i]=(int)GH3[i];
  __syncthreads();
  int2 f3=find256(hist,1024,r2,t,suf,sh2);
  const unsigned T=(pre<<10)|(unsigned)f3.x;
  if (s==0 && t==0){
    float os=0.f;
    for (int b=KW_BW0[L]; b<KW_BW1[L]; ++b) os+=ws[OFF_ONS+b];
    ws[OFF_WSC+L]=(os/(float)KW_N[L])*sqrtf((float)KW_FAN[L])*0.5f;
  }
  const float4* sc4=(const float4*)in.sc[L];
  const float4* sg4=(const float4*)in.sg[L];
  const float4* on4=(const float4*)in.on[L];
  const float4* ze4=(const float4*)in.ze[L];
  float* wout=ws+(L==2?OFF_W3:OFF_W4);
  unsigned short* W1F=(unsigned short*)(ws+OFF_W1M);   // [ocT][h][quad][oc16][8]
  unsigned short* W2F=(unsigned short*)(ws+OFF_W2);    // [kykx][s][h][quad][oc16][8]
  for (int i4=lo+t;i4<hi;i4+=256){
    float4 sv4=sc4[i4], g=sg4[i4], o=on4[i4], z=ze4[i4];
    float sv[4]={sv4.x,sv4.y,sv4.z,sv4.w}, gv[4]={g.x,g.y,g.z,g.w};
    float ov[4]={o.x,o.y,o.z,o.w}, zv[4]={z.x,z.y,z.z,z.w};
    #pragma unroll
    for (int j=0;j<4;++j){
      int i=i4*4+j;
      unsigned u=__float_as_uint(sv[j])&0x7fffffffu;
      float w=gv[j]*((u>=T)? ov[j] : zv[j]);
      if (L==0){
        int oc=i/9; int k=i-oc*9;
        int ocT=oc>>4, ocL=oc&15, quad=k>>3, kj=k&7;
        unsigned short hb=f2bf(w);
        float lo2=w-__uint_as_float((unsigned)hb<<16);
        W1F[((((ocT*2+0)*4+quad)*16+ocL)<<3)+kj]=hb;
        W1F[((((ocT*2+1)*4+quad)*16+ocL)<<3)+kj]=f2bf(lo2);
      } else if (L==1){
        int oc=i/576; int r=i-oc*576; int ic=r/9; int kp=r-ic*9;
        int ss=ic>>5, rem=ic&31, quad=rem>>3, kj=rem&7;
        unsigned short hb=f2bf(w);
        float lo2=w-__uint_as_float((unsigned)hb<<16);
        W2F[(((((kp*2+ss)*2+0)*4+quad)*16+oc)<<3)+kj]=hb;
        W2F[(((((kp*2+ss)*2+1)*4+quad)*16+oc)<<3)+kj]=f2bf(lo2);
      } else {
        int o2;
        if (L==2){ int oc=i/400; int kk=i-oc*400; o2=kk*128+oc; }
        else o2=i;
        wout[o2]=w;
      }
    }
  }
}

// ---------------- KB: conv1 via MFMA -> per-channel BN1 stats partials (1 img/block) ----------------
__global__ __launch_bounds__(256) void kb_kernel(InPtrs in, const float* __restrict__ wsr, float* __restrict__ wsw){
  const int t=threadIdx.x, blk=blockIdx.x;
  __shared__ unsigned short qxs[256];
  __shared__ __align__(16) unsigned PAT[2880];   // patches [pos144][20 dwords = 40 u16, k0..31 used]
  __shared__ float xw[1024];
  const float* pooled=wsr+OFF_POOLED;
  const unsigned* U=(const unsigned*)(wsr+OFF_GMM);
  const float mn0=fdec(U[0]);
  const float mx0=fdec(U[1]);
  const float lvf=(float)((1<<in.qb[0])-1);
  const float s0=(mx0-mn0)/lvf, inv_s0=1.0f/s0, zp0=floorf(mn0/s0);
  const float sv=s0/wsr[OFF_WSC+0];
  if (t<224){
    int row=t>>4, col=t&15;
    float q=0.f;
    if (col<14){ float xx=pooled[(size_t)blk*196+row*14+col]; q=rintf((xx-mn0)*inv_s0)+zp0; }
    qxs[t]=(unsigned short)(__float_as_uint(q)>>16);
  }
  __syncthreads();
  for (int idx=t; idx<2304; idx+=256){
    int pos=idx>>4, kd=idx&15;
    int py=pos/12, px=pos-py*12;
    unsigned c0=0u,c1=0u;
    int k0=kd*2;
    if (k0<9){ int ky=k0/3,kx=k0-ky*3; c0=qxs[(py+ky)*16+px+kx]; }
    if (k0+1<9){ int k1=k0+1; int ky=k1/3,kx=k1-ky*3; c1=qxs[(py+ky)*16+px+kx]; }
    PAT[pos*20+kd]=c0|(c1<<16);
  }
  __syncthreads();
  {
    const int w=t>>6, lane=t&63;
    const int l15=lane&15, quad=lane>>4;
    const unsigned short* W1F=(const unsigned short*)(wsr+OFF_W1M);
    const unsigned short* PATu=(const unsigned short*)PAT;
    #pragma unroll
    for (int ocT=0; ocT<4; ++ocT){
      bf16x8 bh=*(const bf16x8*)(W1F+(((ocT*2+0)*64+lane)<<3));
      bf16x8 bl=*(const bf16x8*)(W1F+(((ocT*2+1)*64+lane)<<3));
      float sum=0.f,sq=0.f,mn=3.4e38f,mx=-3.4e38f;
      for (int tl=w; tl<9; tl+=4){
        bf16x8 a=*(const bf16x8*)(PATu+(tl*16+l15)*40+quad*8);
        f32x4 acc=(f32x4){0.f,0.f,0.f,0.f};
        acc=__builtin_amdgcn_mfma_f32_16x16x32_bf16(a,bh,acc,0,0,0);
        acc=__builtin_amdgcn_mfma_f32_16x16x32_bf16(a,bl,acc,0,0,0);
        #pragma unroll
        for (int r=0;r<4;++r){
          float v=acc[r]*sv;
          sum+=v; sq=fmaf(v,v,sq); mn=fminf(mn,v); mx=fmaxf(mx,v);
        }
      }
      #pragma unroll
      for (int d=16;d<64;d<<=1){
        sum+=__shfl_xor(sum,d);
        sq +=__shfl_xor(sq,d);
        mn=fminf(mn,__shfl_xor(mn,d));
        mx=fmaxf(mx,__shfl_xor(mx,d));
      }
      if (quad==0){
        float* p=xw+((w*4+ocT)*16+l15)*4;
        p[0]=sum; p[1]=sq; p[2]=mn; p[3]=mx;
      }
    }
  }
  __syncthreads();
  if (t<64){
    float sum=0.f,sq=0.f,mn=3.4e38f,mx=-3.4e38f;
    #pragma unroll
    for (int w=0;w<4;++w){
      const float* p=xw+((w*4+(t>>4))*16+(t&15))*4;
      sum+=p[0]; sq+=p[1]; mn=fminf(mn,p[2]); mx=fmaxf(mx,p[3]);
    }
    float* p=wsw+OFF_ST1+((size_t)t*NBB+blk)*4;
    p[0]=sum; p[1]=sq; p[2]=mn; p[3]=mx;
  }
}

// ---------------- kstat ----------------
__global__ __launch_bounds__(256) void kstat_kernel(const float* __restrict__ wsr, float* __restrict__ wsw,
                                                    unsigned long long inoff, int nparts, float Nf,
                                                    unsigned long long outoff, int mmslot){
  const int c=blockIdx.x, t=threadIdx.x;
  __shared__ float red[256];
  const float* p=wsr+inoff+(size_t)c*nparts*4;
  float sum=0.f,sq=0.f,mn=3.4e38f,mx=-3.4e38f;
  for (int i=t;i<nparts;i+=256){
    sum+=p[i*4]; sq+=p[i*4+1];
    mn=fminf(mn,p[i*4+2]); mx=fmaxf(mx,p[i*4+3]);
  }
  float S=blk_sum(sum,red,t);
  float Q=blk_sum(sq,red,t);
  float MN=blk_min(mn,red,t);
  float MX=blk_max(mx,red,t);
  if (t==0){
    float mean=S/Nf;
    float var=fmaxf(Q/Nf-mean*mean,0.f);
    float sd=sqrtf(var+1e-5f);
    float* o=wsw+outoff+c*4;
    float tmn=(MN-mean)/sd, tmx=(MX-mean)/sd;
    o[0]=mean; o[1]=sd; o[2]=tmn; o[3]=tmx;
    unsigned* U=(unsigned*)(wsw+OFF_GMM);
    atomicMin(&U[mmslot],fenc(tmn));
    atomicMax(&U[mmslot+1],fenc(tmx));
  }
}

// ---------------- KC: conv1(MFMA)->bn1/relu/quant->conv2(MFMA)->pool, 1 img/block ----------------
__global__ __launch_bounds__(256) void kc_kernel(InPtrs in, const float* __restrict__ wsr, float* __restrict__ wsw){
  const int t=threadIdx.x, blk=blockIdx.x;
  __shared__ unsigned short qxs[256];
  __shared__ __align__(16) unsigned PAT[2880];           // patches; aliased by c2s after conv1
  __shared__ __align__(16) unsigned short actA[144*72];  // [cell][72: 64 ch + 8 pad] bf16 codes
  __shared__ float sA2[64], sB2[64];
  __shared__ float stsum[16], stsq[16];
  __shared__ unsigned stmn[16], stmx[16];
  float* c2s=(float*)PAT;                                // [oc16][100] conv2 out
  const float* pooled=wsr+OFF_POOLED;
  const unsigned* U=(const unsigned*)(wsr+OFF_GMM);
  const float mn0=fdec(U[0]);
  const float mx0=fdec(U[1]);
  const float rmn=fdec(U[2]);
  const float rmx=fdec(U[3]);
  const float lvf=(float)((1<<in.qb[0])-1);
  const float s0=(mx0-mn0)/lvf, inv_s0=1.0f/s0, zp0=floorf(mn0/s0);
  const float s1w=wsr[OFF_WSC+0], s2w=wsr[OFF_WSC+1];
  const float s2=(fmaxf(rmx,0.f)-fmaxf(rmn,0.f))/lvf;
  const float inv_s2=1.0f/s2;
  const float g2=s2/s2w;
  if (t<64){
    float m=wsr[OFF_BN1+t*4], sd=wsr[OFF_BN1+t*4+1];
    sA2[t]=s0/(s1w*sd);
    sB2[t]=-m/sd;
  }
  if (t<16){ stsum[t]=0.f; stsq[t]=0.f; stmn[t]=0xFFFFFFFFu; stmx[t]=0u; }
  if (t<224){
    int row=t>>4, col=t&15;
    float q=0.f;
    if (col<14){ float xx=pooled[(size_t)blk*196+row*14+col]; q=rintf((xx-mn0)*inv_s0)+zp0; }
    qxs[t]=(unsigned short)(__float_as_uint(q)>>16);
  }
  __syncthreads();
  for (int idx=t; idx<2304; idx+=256){
    int pos=idx>>4, kd=idx&15;
    int py=pos/12, px=pos-py*12;
    unsigned c0=0u,c1=0u;
    int k0=kd*2;
    if (k0<9){ int ky=k0/3,kx=k0-ky*3; c0=qxs[(py+ky)*16+px+kx]; }
    if (k0+1<9){ int k1=k0+1; int ky=k1/3,kx=k1-ky*3; c1=qxs[(py+ky)*16+px+kx]; }
    PAT[pos*20+kd]=c0|(c1<<16);
  }
  __syncthreads();
  // conv1 MFMA + bn/relu/quant -> actA
  {
    const int w=t>>6, lane=t&63;
    const int l15=lane&15, quad=lane>>4;
    const unsigned short* W1F=(const unsigned short*)(wsr+OFF_W1M);
    const unsigned short* PATu=(const unsigned short*)PAT;
    #pragma unroll
    for (int ocT=0; ocT<4; ++ocT){
      bf16x8 bh=*(const bf16x8*)(W1F+(((ocT*2+0)*64+lane)<<3));
      bf16x8 bl=*(const bf16x8*)(W1F+(((ocT*2+1)*64+lane)<<3));
      const int oc=ocT*16+l15;
      const float a2=sA2[oc], b2=sB2[oc];
      for (int tl=w; tl<9; tl+=4){
        bf16x8 a=*(const bf16x8*)(PATu+(tl*16+l15)*40+quad*8);
        f32x4 acc=(f32x4){0.f,0.f,0.f,0.f};
        acc=__builtin_amdgcn_mfma_f32_16x16x32_bf16(a,bh,acc,0,0,0);
        acc=__builtin_amdgcn_mfma_f32_16x16x32_bf16(a,bl,acc,0,0,0);
        #pragma unroll
        for (int r=0;r<4;++r){
          int pos=tl*16+quad*4+r;
          float f=fminf(rintf(fmaxf(fmaf(acc[r],a2,b2),0.f)*inv_s2),lvf);
          actA[pos*72+oc]=(unsigned short)(__float_as_uint(f)>>16);
        }
      }
    }
  }
  __syncthreads();
  // conv2 via MFMA: 7 M-tiles of 16 positions; wave w gets tau=w, w+4
  {
    const int w=t>>6, lane=t&63;
    const int oc=lane&15, quad=lane>>4;
    const unsigned short* W2F=(const unsigned short*)(wsr+OFF_W2);
    const int nT=(w<3)?2:1;
    int abase[2]; int taus[2];
    for (int i=0;i<nT;++i){
      int tau=w+i*4;
      int posb=tau*16+(lane&15);
      int pc=posb>99?99:posb;
      int py=pc/10, px=pc-py*10;
      abase[i]=(py*12+px)*72+quad*8;
      taus[i]=tau;
    }
    f32x4 acc[2];
    acc[0]=(f32x4){0.f,0.f,0.f,0.f};
    acc[1]=(f32x4){0.f,0.f,0.f,0.f};
    #pragma unroll 1
    for (int kykx=0;kykx<9;++kykx){
      const int co=((kykx/3)*12+(kykx%3))*72;
      #pragma unroll
      for (int s=0;s<2;++s){
        bf16x8 bh=*(const bf16x8*)(W2F+((((kykx*2+s)*2+0)*64+lane)<<3));
        bf16x8 bl=*(const bf16x8*)(W2F+((((kykx*2+s)*2+1)*64+lane)<<3));
        #pragma unroll
        for (int i=0;i<2;++i){
          if (i<nT){
            bf16x8 a=*(const bf16x8*)(actA+abase[i]+co+s*32);
            acc[i]=__builtin_amdgcn_mfma_f32_16x16x32_bf16(a,bh,acc[i],0,0,0);
            acc[i]=__builtin_amdgcn_mfma_f32_16x16x32_bf16(a,bl,acc[i],0,0,0);
          }
        }
      }
    }
    __syncthreads();   // PAT + actA reads done -> safe to write c2s (aliases PAT)
    for (int i=0;i<nT;++i){
      int pos4=taus[i]*16+quad*4;
      if (pos4<100){
        float4* dst=(float4*)&c2s[oc*100+pos4];
        *dst=make_float4(acc[i].x*g2,acc[i].y*g2,acc[i].z*g2,acc[i].w*g2);
      }
    }
  }
  __syncthreads();
  for (int i=t;i<400;i+=256){
    int ch=i/25, pp=i-ch*25;
    int py=pp/5, px=pp-py*5;
    const float* cc=c2s+ch*100;
    int base=py*20+px*2;
    float v=fmaxf(fmaxf(cc[base],cc[base+1]),fmaxf(cc[base+10],cc[base+11]));
    wsw[OFF_Y2P+(size_t)blk*400+i]=v;
    atomicAdd(&stsum[ch],v);
    atomicAdd(&stsq[ch],v*v);
    atomicMin(&stmn[ch],fenc(v));
    atomicMax(&stmx[ch],fenc(v));
  }
  __syncthreads();
  if (t<16){
    float* p=wsw+OFF_ST2+((size_t)t*NBC+blk)*4;
    p[0]=stsum[t]; p[1]=stsq[t]; p[2]=fdec(stmn[t]); p[3]=fdec(stmx[t]);
  }
}

// ---------------- KE: bn2/relu/quant -> fc1 -> relu, 8 img/block (2 img/wave) ----------------
__global__ __launch_bounds__(256) void ke_kernel(InPtrs in, const float* __restrict__ wsr, float* __restrict__ wsw){
  const int t=threadIdx.x, blk=blockIdx.x;
  __shared__ __align__(16) float xs[3200];
  __shared__ float sm[16], sisd[16];
  const unsigned* U=(const unsigned*)(wsr+OFF_GMM);
  const float lvf=(float)((1<<in.qb[0])-1);
  const float rmn=fdec(U[4]);
  const float rmx=fdec(U[5]);
  if (t<16){ sm[t]=wsr[OFF_BN2+t*4]; sisd[t]=1.0f/wsr[OFF_BN2+t*4+1]; }
  const float s3=(fmaxf(rmx,0.f)-fmaxf(rmn,0.f))/lvf;
  const float inv_s3=1.0f/s3;
  const float inv_s3w=1.0f/wsr[OFF_WSC+2];
  const int b0=blk*8;
  __syncthreads();
  for (int i=t;i<3200;i+=256){
    int img=i/400, k=i-img*400;
    int ch=k/25;
    float y=wsr[OFF_Y2P+(size_t)(b0+img)*400+k];
    float bn=(y-sm[ch])*sisd[ch];
    float r=fmaxf(bn,0.f);
    xs[i]=fminf(rintf(r*inv_s3),lvf)*s3;
  }
  __syncthreads();
  const int w=t>>6, lane=t&63;
  const float* xA=xs+(w*2)*400;
  const float* xB=xs+(w*2+1)*400;
  const float* w3=wsr+OFF_W3;
  float aA0=0.f,aA1=0.f,aB0=0.f,aB1=0.f;
  #pragma unroll 2
  for (int k=0;k<400;k+=4){
    float4 va=*(const float4*)(xA+k);
    float4 vb=*(const float4*)(xB+k);
    float2 w0=*(const float2*)(w3+(k+0)*128+lane*2);
    float2 w1=*(const float2*)(w3+(k+1)*128+lane*2);
    float2 w2=*(const float2*)(w3+(k+2)*128+lane*2);
    float2 wv3=*(const float2*)(w3+(k+3)*128+lane*2);
    aA0=fmaf(va.x,w0.x,aA0); aA1=fmaf(va.x,w0.y,aA1);
    aB0=fmaf(vb.x,w0.x,aB0); aB1=fmaf(vb.x,w0.y,aB1);
    aA0=fmaf(va.y,w1.x,aA0); aA1=fmaf(va.y,w1.y,aA1);
    aB0=fmaf(vb.y,w1.x,aB0); aB1=fmaf(vb.y,w1.y,aB1);
    aA0=fmaf(va.z,w2.x,aA0); aA1=fmaf(va.z,w2.y,aA1);
    aB0=fmaf(vb.z,w2.x,aB0); aB1=fmaf(vb.z,w2.y,aB1);
    aA0=fmaf(va.w,wv3.x,aA0); aA1=fmaf(va.w,wv3.y,aA1);
    aB0=fmaf(vb.w,wv3.x,aB0); aB1=fmaf(vb.w,wv3.y,aB1);
  }
  float hA0=fmaxf(aA0*inv_s3w,0.f), hA1=fmaxf(aA1*inv_s3w,0.f);
  float hB0=fmaxf(aB0*inv_s3w,0.f), hB1=fmaxf(aB1*inv_s3w,0.f);
  *(float2*)(wsw+OFF_H3+(size_t)(b0+w*2)*128+lane*2)=make_float2(hA0,hA1);
  *(float2*)(wsw+OFF_H3+(size_t)(b0+w*2+1)*128+lane*2)=make_float2(hB0,hB1);
  float hmn=fminf(fminf(hA0,hA1),fminf(hB0,hB1));
  float hmx=fmaxf(fmaxf(hA0,hA1),fmaxf(hB0,hB1));
  #pragma unroll
  for (int d=1;d<64;d<<=1){
    hmn=fminf(hmn,__shfl_xor(hmn,d));
    hmx=fmaxf(hmx,__shfl_xor(hmx,d));
  }
  if (lane==0){
    unsigned* Uw=(unsigned*)(wsw+OFF_GMM);
    atomicMin(&Uw[6],fenc(hmn));
    atomicMax(&Uw[7],fenc(hmx));
  }
}

// ---------------- KF: quant -> fc2 -> log_softmax; 64 rows/block, 4 lanes/row ----------------
__global__ __launch_bounds__(256) void kf_kernel(InPtrs in, const float* __restrict__ wsr, float* __restrict__ out){
  const int t=threadIdx.x, blk=blockIdx.x;
  __shared__ float w4s[1280];
  const unsigned* U=(const unsigned*)(wsr+OFF_GMM);
  const float lvf=(float)((1<<in.qb[0])-1);
  const float hmn=fdec(U[6]);
  const float hmx=fdec(U[7]);
  for (int i=t;i<1280;i+=256) w4s[i]=wsr[OFF_W4+i];
  const float s4=(hmx-hmn)/lvf;
  const float inv_s4=1.0f/s4;
  const float inv_s4w=1.0f/wsr[OFF_WSC+3];
  __syncthreads();
  const int row=blk*64+(t>>2), l4=t&3;
  const float4* hr4=(const float4*)(wsr+OFF_H3+(size_t)row*128);
  float acc[10];
  #pragma unroll
  for (int j=0;j<10;++j) acc[j]=0.f;
  #pragma unroll 2
  for (int j=0;j<8;++j){
    float4 v=hr4[l4*8+j];
    int kb=(l4*8+j)*4;
    float q0=fminf(rintf(v.x*inv_s4),lvf)*s4;
    float q1=fminf(rintf(v.y*inv_s4),lvf)*s4;
    float q2=fminf(rintf(v.z*inv_s4),lvf)*s4;
    float q3=fminf(rintf(v.w*inv_s4),lvf)*s4;
    #pragma unroll
    for (int o=0;o<10;++o){
      const float* wr=w4s+o*128+kb;
      acc[o]=fmaf(q0,wr[0],acc[o]);
      acc[o]=fmaf(q1,wr[1],acc[o]);
      acc[o]=fmaf(q2,wr[2],acc[o]);
      acc[o]=fmaf(q3,wr[3],acc[o]);
    }
  }
  #pragma unroll
  for (int o=0;o<10;++o){
    acc[o]+=__shfl_xor(acc[o],1);
    acc[o]+=__shfl_xor(acc[o],2);
  }
  if (l4==0){
    float mx=-3.4e38f;
    #pragma unroll
    for (int o=0;o<10;++o){ acc[o]*=inv_s4w; mx=fmaxf(mx,acc[o]); }
    float se=0.f;
    #pragma unroll
    for (int o=0;o<10;++o) se+=expf(acc[o]-mx);
    const float ls=logf(se);
    #pragma unroll
    for (int o=0;o<10;++o) out[row*10+o]=acc[o]-mx-ls;
  }
}

extern "C" void kernel_launch(void* const* d_in, const int* in_sizes, int n_in,
                              void* d_out, int out_size, void* d_ws, size_t ws_size,
                              hipStream_t stream){
  (void)in_sizes; (void)n_in; (void)out_size; (void)ws_size;
  InPtrs P;
  P.x=(const float*)d_in[0];
  for (int l=0;l<4;++l){
    P.sc[l]=(const float*)d_in[1+l*4];
    P.sg[l]=(const float*)d_in[2+l*4];
    P.on[l]=(const float*)d_in[3+l*4];
    P.ze[l]=(const float*)d_in[4+l*4];
  }
  P.qb=(const int*)d_in[17];
  float* ws=(float*)d_ws;

  hipLaunchKernelGGL(ka_kernel,   dim3(NBA+NBW), dim3(256), 0, stream, P, ws);
  hipLaunchKernelGGL(kw2a_kernel, dim3(4),       dim3(256), 0, stream, ws);
  hipLaunchKernelGGL(kwp2_kernel, dim3(NBW),     dim3(256), 0, stream, P, ws);
  hipLaunchKernelGGL(kwp3_kernel, dim3(NBW),     dim3(256), 0, stream, P, ws);
  hipLaunchKernelGGL(kw3_kernel,  dim3(NBW),     dim3(256), 0, stream, P, ws);
  hipLaunchKernelGGL(kb_kernel,   dim3(NBB),     dim3(256), 0, stream, P, ws, ws);
  hipLaunchKernelGGL(kstat_kernel, dim3(64), dim3(256), 0, stream, ws, ws,
                     (unsigned long long)OFF_ST1, NBB, 4096.f*144.f, (unsigned long long)OFF_BN1, 2);
  hipLaunchKernelGGL(kc_kernel,   dim3(NBC),     dim3(256), 0, stream, P, ws, ws);
  hipLaunchKernelGGL(kstat_kernel, dim3(16), dim3(256), 0, stream, ws, ws,
                     (unsigned long long)OFF_ST2, NBC, 4096.f*25.f, (unsigned long long)OFF_BN2, 4);
  hipLaunchKernelGGL(ke_kernel,   dim3(NBE),     dim3(256), 0, stream, P, ws, ws);
  hipLaunchKernelGGL(kf_kernel,   dim3(64),      dim3(256), 0, stream, P, ws, (float*)d_out);
}